// Round 4
// baseline (18973.204 us; speedup 1.0000x reference)
//
#include <hip/hip_runtime.h>
#include <hip/hip_bf16.h>
#include <math.h>

// RITS-style RNN + late attention, fused persistent kernel. Round 7
// (= round-6 resubmission; round-6 bench was an infra failure, no counters).
//  - Round-5 structure (8 batch rows/block, 128 blocks) with the spill fixed:
//    __launch_bounds__(512, 1). Round 5's (512,2) capped VGPRs at 128, which
//    spilled the 120 O-accumulator registers to scratch -> 8.2 GB/dispatch of
//    HBM scratch traffic (FETCH 8.58 GB matched 120regs*512t*128blk*256steps).
//    With min-1-wave/EU the compiler can allocate ~200-240 VGPRs; <=256 keeps
//    2 waves/SIMD co-resident, and LDS (85 KB) already limits to 1 block/CU.
//  - Rationale unchanged: halve per-XCD L2 weight-fragment streaming
//    (b5 768KB + b6/b3/b2/b7 ~265KB per block per step; 16.8 MB/XCD/step at
//    128 blocks vs 33.6 at 256). MFMA tiles carry 8 real rows of 16.
//  - Writer lanes lq<2 (C rows lq*4+r = 0..7); LSTM/attention threads own
//    2 rows x 2 cols (4 h-units, 4x30 O accumulators = 120 VGPR).
// ws layout: f32 ws[0]=xl ws[1]=y ws[2]=tr_sum ws[16..272)=msum; then bf16
// B-frag tensors at WS_B5/B6/B3/B2/B7 (total ~1.03 MB).

#define BB 1024
#define SS 256
#define NF 64
#define HD 256
#define DAA 350
#define DRR 30
#define RPB 8

#define WS_B5_OFS 4096
#define WS_B5_ELEMS (64 * 12 * 64 * 8)   // gates: 64 n-tiles x 12 k-tiles
#define WS_B6_OFS (WS_B5_OFS + WS_B5_ELEMS * 2)
#define WS_B6_ELEMS (22 * 8 * 64 * 8)    // Ws1: 22 n-tiles x 8 k-tiles
#define WS_B3_OFS (WS_B6_OFS + WS_B6_ELEMS * 2)
#define WS_B3_ELEMS (4 * 8 * 64 * 8)     // hist: 4 n-tiles x 8 k-tiles
#define WS_B2_OFS (WS_B3_OFS + WS_B3_ELEMS * 2)
#define WS_B2_ELEMS (16 * 2 * 64 * 8)    // td_h: 16 n-tiles x 2 k-tiles
#define WS_B7_OFS (WS_B2_OFS + WS_B2_ELEMS * 2)
#define WS_B7_ELEMS (2 * 11 * 64 * 8)    // Ws2: 2 n-tiles x 11 k-tiles (K=350->352)
#define CW_TOTAL (WS_B5_ELEMS + WS_B6_ELEMS + WS_B3_ELEMS + WS_B2_ELEMS + WS_B7_ELEMS)

typedef __attribute__((ext_vector_type(8))) short bf16x8;
typedef __attribute__((ext_vector_type(4))) float f32x4;

__device__ __forceinline__ float dot4f(float4 a, float4 b) {
  return fmaf(a.x, b.x, fmaf(a.y, b.y, fmaf(a.z, b.z, a.w * b.w)));
}

__device__ __forceinline__ short f2bs(float v) {
  __hip_bfloat16 t = __float2bfloat16(v);
  return *reinterpret_cast<short*>(&t);
}

__device__ __forceinline__ float lstm_unit(float gi, float gf, float gg,
                                           float go, float& c) {
  float ig = 1.f / (1.f + expf(-gi));
  float fg = 1.f / (1.f + expf(-gf));
  float og = 1.f / (1.f + expf(-go));
  c = fg * c + ig * tanhf(gg);
  return og * tanhf(c);
}

__global__ __launch_bounds__(256) void convert_weights(
    const float* __restrict__ W_ih, const float* __restrict__ W_hh,
    const float* __restrict__ Ws1_W, const float* __restrict__ hist_W,
    const float* __restrict__ td_h_W, const float* __restrict__ Ws2_W,
    short* __restrict__ b5, short* __restrict__ b6,
    short* __restrict__ b3, short* __restrict__ b2, short* __restrict__ b7)
{
  int idx = blockIdx.x * 256 + threadIdx.x;
  if (idx < WS_B5_ELEMS) {
    int j = idx & 7; int e8 = idx >> 3; int lane = e8 & 63; int tile = e8 >> 6;
    int kt = tile % 12, nt = tile / 12;
    int g = nt * 16 + (lane & 15);
    int k = kt * 32 + (lane >> 4) * 8 + j;  // [c_c(64)|m(64)|h(256)]
    float v = (k < 128) ? W_ih[g * 128 + k] : W_hh[g * 256 + (k - 128)];
    b5[idx] = f2bs(v);
  } else if (idx < WS_B5_ELEMS + WS_B6_ELEMS) {
    int i = idx - WS_B5_ELEMS;
    int j = i & 7; int e8 = i >> 3; int lane = e8 & 63; int tile = e8 >> 6;
    int kt = tile & 7, nt = tile >> 3;
    int a = nt * 16 + (lane & 15);
    int k = kt * 32 + (lane >> 4) * 8 + j;
    float v = (a < DAA) ? Ws1_W[a * 256 + k] : 0.f;
    b6[i] = f2bs(v);
  } else if (idx < WS_B5_ELEMS + WS_B6_ELEMS + WS_B3_ELEMS) {
    int i = idx - WS_B5_ELEMS - WS_B6_ELEMS;
    int j = i & 7; int e8 = i >> 3; int lane = e8 & 63; int tile = e8 >> 6;
    int kt = tile & 7, nt = tile >> 3;
    int n = nt * 16 + (lane & 15);
    int k = kt * 32 + (lane >> 4) * 8 + j;
    b3[i] = f2bs(hist_W[n * 256 + k]);
  } else if (idx < WS_B5_ELEMS + WS_B6_ELEMS + WS_B3_ELEMS + WS_B2_ELEMS) {
    int i = idx - WS_B5_ELEMS - WS_B6_ELEMS - WS_B3_ELEMS;
    int j = i & 7; int e8 = i >> 3; int lane = e8 & 63; int tile = e8 >> 6;
    int kt = tile & 1, nt = tile >> 1;
    int g = nt * 16 + (lane & 15);
    int k = kt * 32 + (lane >> 4) * 8 + j;
    b2[i] = f2bs(td_h_W[g * 64 + k]);
  } else if (idx < CW_TOTAL) {
    int i = idx - WS_B5_ELEMS - WS_B6_ELEMS - WS_B3_ELEMS - WS_B2_ELEMS;
    int j = i & 7; int e8 = i >> 3; int lane = e8 & 63; int tile = e8 >> 6;
    int kt = tile % 11, nt = tile / 11;
    int r = nt * 16 + (lane & 15);
    int k = kt * 32 + (lane >> 4) * 8 + j;
    float v = (r < DRR && k < DAA) ? Ws2_W[r * DAA + k] : 0.f;
    b7[i] = f2bs(v);
  }
}

__global__ __launch_bounds__(256) void prep_kernel(
    const float* __restrict__ masks, const float* __restrict__ is_train,
    float* __restrict__ ws)
{
  __shared__ float red[256];
  const int t = blockIdx.x;
  const int tid = threadIdx.x;
  float s = 0.f;
  for (int idx = tid; idx < BB * NF; idx += 256) {
    int b = idx >> 6, n = idx & 63;
    s += masks[(size_t)b * (SS * NF) + (size_t)t * NF + n];
  }
  red[tid] = s;
  __syncthreads();
  for (int off = 128; off > 0; off >>= 1) {
    if (tid < off) red[tid] += red[tid + off];
    __syncthreads();
  }
  if (tid == 0) ws[16 + t] = red[0] + 1e-5f;
  if (blockIdx.x == 0) {
    __syncthreads();
    float ts = 0.f;
    for (int idx = tid; idx < BB; idx += 256) ts += is_train[idx];
    red[tid] = ts;
    __syncthreads();
    for (int off = 128; off > 0; off >>= 1) {
      if (tid < off) red[tid] += red[tid + off];
      __syncthreads();
    }
    if (tid == 0) { ws[2] = red[0]; ws[0] = 0.f; ws[1] = 0.f; }
  }
}

__global__ __launch_bounds__(512, 1) void rits_main(
    const float* __restrict__ values, const float* __restrict__ masks_g,
    const float* __restrict__ deltas, const float* __restrict__ labels,
    const float* __restrict__ is_train,
    const float* __restrict__ td_h_b, const float* __restrict__ td_x_W,
    const float* __restrict__ td_x_b, const float* __restrict__ hist_b,
    const float* __restrict__ feat_W, const float* __restrict__ feat_b,
    const float* __restrict__ comb_W, const float* __restrict__ comb_b,
    const float* __restrict__ b_ih, const float* __restrict__ b_hh,
    const float* __restrict__ Ws1_b,
    const float* __restrict__ Ws2_W, const float* __restrict__ Ws2_b,
    const float* __restrict__ out_W, const float* __restrict__ out_b,
    float* __restrict__ out, float* __restrict__ ws)
{
  __shared__ __align__(16) float sh_a[RPB][384];   // f32: [unused|m|h]
  __shared__ __align__(16) short sh_ab[16][392];   // bf16 [c_c|m|h], rows 8+ zero
  __shared__ __align__(16) short sh_db[16][72];    // bf16 d, rows 8+ zero
  __shared__ __align__(16) short sh_s1b[16][392];  // bf16 s1 (tanh), rows 8+ zero
  __shared__ __align__(16) float sh_x[RPB][NF];
  __shared__ __align__(16) float sh_d[RPB][NF];
  __shared__ __align__(16) float sh_xc[RPB][NF];
  __shared__ __align__(16) float sh_gx[RPB][NF];
  __shared__ __align__(16) float sh_xh[RPB][NF];
  __shared__ __align__(16) float sh_gates[RPB][1024];
  __shared__ float sh_w[RPB][32];
  __shared__ float sh_scale[RPB][32];
  __shared__ float sh_M[RPB][32];
  __shared__ float sh_L[RPB][32];
  __shared__ float sh_msum;

  const int tid = threadIdx.x;
  const int b0 = blockIdx.x * RPB;
  const int wv = tid >> 6;       // wave 0..7
  const int lane = tid & 63;
  const int lm = lane & 15;      // m/n within MFMA tile
  const int lq = lane >> 4;      // quad
  const int row = tid >> 7;      // LSTM/attention base row (handles row, row+4)
  const int j = tid & 127;
  const int jA = j, jB = j + 128;
  const int row2 = tid >> 6;     // staging/feature row 0..7
  const int nn = tid & 63;

  const bf16x8* b5 = (const bf16x8*)((const char*)ws + WS_B5_OFS);
  const bf16x8* b6 = (const bf16x8*)((const char*)ws + WS_B6_OFS);
  const bf16x8* b3 = (const bf16x8*)((const char*)ws + WS_B3_OFS);
  const bf16x8* b2 = (const bf16x8*)((const char*)ws + WS_B2_OFS);
  const bf16x8* b7 = (const bf16x8*)((const char*)ws + WS_B7_OFS);

  // ---- init LDS
  for (int i = tid; i < 16 * 392; i += 512) (&sh_ab[0][0])[i] = 0;
  for (int i = tid; i < 16 * 392; i += 512) (&sh_s1b[0][0])[i] = 0;
  for (int i = tid; i < 16 * 72; i += 512) (&sh_db[0][0])[i] = 0;
  for (int i = tid; i < RPB * 384; i += 512) (&sh_a[0][0])[i] = 0.f;
  if (tid < RPB * 32) {
    int rr = tid >> 5, q = tid & 31;
    sh_M[rr][q] = -1e30f;
    sh_L[rr][q] = 0.f;
  }

  // per-thread cached scalars
  const float tdxw  = td_x_W[nn * NF + nn];
  const float tdxb  = td_x_b[nn];
  const float featb = feat_b[nn];
  const float featd = feat_W[nn * NF + nn];
  const float combb = comb_b[nn];
  float bgA[4], bgB[4];
  #pragma unroll
  for (int q = 0; q < 4; ++q) {
    bgA[q] = b_ih[q * 256 + jA] + b_hh[q * 256 + jA];
    bgB[q] = b_ih[q * 256 + jB] + b_hh[q * 256 + jB];
  }

  // hoisted per-lane bias constants for MFMA writer lanes (lq<2)
  float thb[2];
  thb[0] = td_h_b[(wv * 2 + 0) * 16 + lm];
  thb[1] = td_h_b[(wv * 2 + 1) * 16 + lm];
  float hbv = 0.f;
  if (wv < 4) hbv = hist_b[wv * 16 + lm];
  float w1b[3] = {0.f, 0.f, 0.f};
  #pragma unroll
  for (int ii = 0; ii < 3; ++ii) {
    int nt = wv + 8 * ii;
    int a = nt * 16 + lm;
    if (nt < 22 && a < DAA) w1b[ii] = Ws1_b[a];
  }
  float w2bv = 0.f;
  if (wv < 2) {
    int r = wv * 16 + lm;
    if (r < DRR) w2bv = Ws2_b[r];
  }

  float cA0 = 0.f, cB0 = 0.f, cA1 = 0.f, cB1 = 0.f;
  float OA0[DRR], OB0[DRR], OA1[DRR], OB1[DRR];
  #pragma unroll
  for (int r = 0; r < DRR; ++r) { OA0[r] = 0.f; OB0[r] = 0.f; OA1[r] = 0.f; OB1[r] = 0.f; }
  double lossAcc = 0.0;

  // ---- prefetch t=0 inputs into registers (each thread owns (row2, nn))
  float pv_x, pv_d, pv_m, pv_msum = 0.f;
  {
    size_t g = (size_t)(b0 + row2) * (SS * NF) + nn;
    pv_x = values[g];
    pv_d = deltas[g];
    pv_m = masks_g[g];
  }
  if (tid == 0) pv_msum = ws[16];

  __syncthreads();

  for (int t = 0; t < SS; ++t) {
    // ---- stage prefetched x,d,m (f32 + bf16 mirrors)
    sh_x[row2][nn] = pv_x;
    sh_d[row2][nn] = pv_d;
    sh_db[row2][nn] = f2bs(pv_d);
    sh_a[row2][64 + nn] = pv_m;
    sh_ab[row2][64 + nn] = f2bs(pv_m);
    if (tid == 0) sh_msum = pv_msum;
    __syncthreads(); // S1

    // ---- issue next-step input loads; latency hides under phases 2..8
    if (t + 1 < SS) {
      size_t g = (size_t)(b0 + row2) * (SS * NF) + (size_t)(t + 1) * NF + nn;
      pv_x = values[g];
      pv_d = deltas[g];
      pv_m = masks_g[g];
      if (tid == 0) pv_msum = ws[16 + t + 1];
    }

    // ---- phase 2: gamma_h via MFMA (16 n-tiles over h); writers decay h.
    {
      bf16x8 dfr[2];
      #pragma unroll
      for (int kt = 0; kt < 2; ++kt)
        dfr[kt] = *(const bf16x8*)(&sh_db[lm][0] + kt * 32 + lq * 8);
      #pragma unroll
      for (int ntl = 0; ntl < 2; ++ntl) {
        int nt = wv * 2 + ntl;
        f32x4 acc = {0.f, 0.f, 0.f, 0.f};
        const bf16x8* bp = b2 + (size_t)(nt * 2) * 64 + lane;
        acc = __builtin_amdgcn_mfma_f32_16x16x32_bf16(dfr[0], bp[0], acc, 0, 0, 0);
        acc = __builtin_amdgcn_mfma_f32_16x16x32_bf16(dfr[1], bp[64], acc, 0, 0, 0);
        if (lq < 2) {
          int g = nt * 16 + lm;
          float bias = thb[ntl];
          #pragma unroll
          for (int r = 0; r < 4; ++r) {
            int rr = lq * 4 + r;
            float gam = expf(-fmaxf(acc[r] + bias, 0.f));
            float h = sh_a[rr][128 + g] * gam;
            sh_a[rr][128 + g] = h;
            sh_ab[rr][128 + g] = f2bs(h);
          }
        }
      }
      float v = sh_d[row2][nn] * tdxw + tdxb;  // diag only
      sh_gx[row2][nn] = expf(-fmaxf(v, 0.f));
    }
    __syncthreads(); // S2

    // ---- phase 3: x_h = h @ hist_W^T + b via MFMA (waves 0-3, 1 tile each)
    if (wv < 4) {
      int nt = wv;
      f32x4 acc = {0.f, 0.f, 0.f, 0.f};
      const bf16x8* bp = b3 + (size_t)(nt * 8) * 64 + lane;
      #pragma unroll
      for (int kt = 0; kt < 8; ++kt) {
        bf16x8 a = *(const bf16x8*)(&sh_ab[lm][128] + kt * 32 + lq * 8);
        acc = __builtin_amdgcn_mfma_f32_16x16x32_bf16(a, bp[kt * 64], acc, 0, 0, 0);
      }
      if (lq < 2) {
        int n = nt * 16 + lm;
        float lterm = 0.f;
        #pragma unroll
        for (int r = 0; r < 4; ++r) {
          int rr = lq * 4 + r;
          float xh = acc[r] + hbv;
          sh_xh[rr][n] = xh;
          float m = sh_a[rr][64 + n], x = sh_x[rr][n];
          sh_xc[rr][n] = m * x + (1.f - m) * xh;
          lterm += fabsf(x - xh) * m;
        }
        lossAcc += (double)(lterm / sh_msum);
      }
    }
    __syncthreads(); // S3

    // ---- phase 4: z_h (zero-diag feat), alpha, c_h, c_c (f32 VALU, all 512)
    {
      const float4* xc4 = (const float4*)&sh_xc[row2][0];
      const float4* gx4 = (const float4*)&sh_gx[row2][0];
      const float4* mm4 = (const float4*)&sh_a[row2][64];
      const float4* fW  = (const float4*)(feat_W + nn * NF);
      const float4* cW0 = (const float4*)(comb_W + nn * 2 * NF);
      const float4* cW1 = (const float4*)(comb_W + nn * 2 * NF + NF);
      float az = 0.f, aa = 0.f;
      #pragma unroll
      for (int k = 0; k < 16; ++k) {
        az += dot4f(xc4[k], fW[k]);
        aa += dot4f(gx4[k], cW0[k]);
        aa += dot4f(mm4[k], cW1[k]);
      }
      float xcn = sh_xc[row2][nn];
      float zh = az - xcn * featd + featb;
      float alpha = aa + combb;
      float xh = sh_xh[row2][nn];
      float chv = alpha * zh + (1.f - alpha) * xh;
      float m = sh_a[row2][64 + nn], x = sh_x[row2][nn];
      float ccv = m * x + (1.f - m) * chv;
      sh_ab[row2][nn] = f2bs(ccv);
      out[1 + BB + ((size_t)(b0 + row2) * SS + t) * NF + nn] = ccv;
      float lsum = (fabsf(x - zh) + fabsf(x - chv)) * m;
      lossAcc += (double)(lsum / sh_msum);
    }
    __syncthreads(); // S4

    // ---- phase 5: gates via MFMA. Wave wv owns n-tiles wv*8..wv*8+7.
    {
      bf16x8 afr[12];
      #pragma unroll
      for (int kt = 0; kt < 12; ++kt)
        afr[kt] = *(const bf16x8*)(&sh_ab[lm][0] + kt * 32 + lq * 8);
      #pragma unroll 2
      for (int ntl = 0; ntl < 8; ++ntl) {
        int nt = wv * 8 + ntl;
        f32x4 acc = {0.f, 0.f, 0.f, 0.f};
        const bf16x8* bp = b5 + (size_t)(nt * 12) * 64 + lane;
        #pragma unroll
        for (int kt = 0; kt < 12; ++kt)
          acc = __builtin_amdgcn_mfma_f32_16x16x32_bf16(afr[kt], bp[kt * 64], acc, 0, 0, 0);
        if (lq < 2) {
          int n = nt * 16 + lm;
          #pragma unroll
          for (int r = 0; r < 4; ++r) sh_gates[lq * 4 + r][n] = acc[r];
        }
      }
    }
    __syncthreads(); // S5

    // ---- LSTM state update: 4 h-units/thread (rows row, row+4; cols jA, jB)
    float hnA0, hnB0, hnA1, hnB1;
    {
      hnA0 = lstm_unit(sh_gates[row][jA] + bgA[0], sh_gates[row][256 + jA] + bgA[1],
                       sh_gates[row][512 + jA] + bgA[2], sh_gates[row][768 + jA] + bgA[3], cA0);
      hnB0 = lstm_unit(sh_gates[row][jB] + bgB[0], sh_gates[row][256 + jB] + bgB[1],
                       sh_gates[row][512 + jB] + bgB[2], sh_gates[row][768 + jB] + bgB[3], cB0);
      hnA1 = lstm_unit(sh_gates[row + 4][jA] + bgA[0], sh_gates[row + 4][256 + jA] + bgA[1],
                       sh_gates[row + 4][512 + jA] + bgA[2], sh_gates[row + 4][768 + jA] + bgA[3], cA1);
      hnB1 = lstm_unit(sh_gates[row + 4][jB] + bgB[0], sh_gates[row + 4][256 + jB] + bgB[1],
                       sh_gates[row + 4][512 + jB] + bgB[2], sh_gates[row + 4][768 + jB] + bgB[3], cB1);
      sh_a[row][128 + jA] = hnA0;
      sh_a[row][128 + jB] = hnB0;
      sh_a[row + 4][128 + jA] = hnA1;
      sh_a[row + 4][128 + jB] = hnB1;
      sh_ab[row][128 + jA] = f2bs(hnA0);
      sh_ab[row][128 + jB] = f2bs(hnB0);
      sh_ab[row + 4][128 + jA] = f2bs(hnA1);
      sh_ab[row + 4][128 + jB] = f2bs(hnB1);
    }
    __syncthreads(); // S6

    // ---- phase 6: s1 = tanh(h @ Ws1^T + b1) via MFMA (22 tiles), bf16 out
    {
      bf16x8 hfr[8];
      #pragma unroll
      for (int kt = 0; kt < 8; ++kt)
        hfr[kt] = *(const bf16x8*)(&sh_ab[lm][128] + kt * 32 + lq * 8);
      #pragma unroll
      for (int ii = 0; ii < 3; ++ii) {
        int nt = wv + 8 * ii;
        if (nt < 22) {
          f32x4 acc = {0.f, 0.f, 0.f, 0.f};
          const bf16x8* bp = b6 + (size_t)(nt * 8) * 64 + lane;
          #pragma unroll
          for (int kt = 0; kt < 8; ++kt)
            acc = __builtin_amdgcn_mfma_f32_16x16x32_bf16(hfr[kt], bp[kt * 64], acc, 0, 0, 0);
          if (lq < 2) {
            int a = nt * 16 + lm;
            if (a < DAA) {
              float bias = w1b[ii];
              #pragma unroll
              for (int r = 0; r < 4; ++r)
                sh_s1b[lq * 4 + r][a] = f2bs(tanhf(acc[r] + bias));
            }
          }
        }
      }
    }
    __syncthreads(); // S7

    // ---- phase 7: scores via MFMA (2 n-tiles x 11 k-tiles, waves 0-1) +
    //      online-softmax state (M, L, scale, w) for rows 0..7
    if (wv < 2) {
      f32x4 acc = {0.f, 0.f, 0.f, 0.f};
      const bf16x8* bp = b7 + (size_t)(wv * 11) * 64 + lane;
      #pragma unroll
      for (int kt = 0; kt < 11; ++kt) {
        bf16x8 a = *(const bf16x8*)(&sh_s1b[lm][0] + kt * 32 + lq * 8);
        acc = __builtin_amdgcn_mfma_f32_16x16x32_bf16(a, bp[kt * 64], acc, 0, 0, 0);
      }
      if (lq < 2) {
        int r = wv * 16 + lm;
        if (r < DRR) {
          #pragma unroll
          for (int q = 0; q < 4; ++q) {
            int rr = lq * 4 + q;
            float sc = acc[q] + w2bv;
            float Mo = sh_M[rr][r];
            float Mn = fmaxf(Mo, sc);
            float scl = expf(Mo - Mn);
            float w = expf(sc - Mn);
            sh_M[rr][r] = Mn;
            sh_L[rr][r] = sh_L[rr][r] * scl + w;
            sh_scale[rr][r] = scl;
            sh_w[rr][r] = w;
          }
        }
      }
    }
    __syncthreads(); // S8

    // ---- phase 8: O[r] = O[r]*scale + w*h (registers; LDS broadcast)
    #pragma unroll
    for (int r = 0; r < DRR; ++r) {
      float s0 = sh_scale[row][r], w0 = sh_w[row][r];
      float s1 = sh_scale[row + 4][r], w1 = sh_w[row + 4][r];
      OA0[r] = OA0[r] * s0 + w0 * hnA0;
      OB0[r] = OB0[r] * s0 + w0 * hnB0;
      OA1[r] = OA1[r] * s1 + w1 * hnA1;
      OB1[r] = OB1[r] * s1 + w1 * hnB1;
    }
  }

  // ---- finalize: y_h = out_W . (O/L), bce, predictions, loss reduce
  float pA0 = 0.f, pB0 = 0.f, pA1 = 0.f, pB1 = 0.f;
  #pragma unroll
  for (int r = 0; r < DRR; ++r) {
    float iL0 = 1.f / sh_L[row][r];
    float iL1 = 1.f / sh_L[row + 4][r];
    float wA = out_W[r * HD + jA];
    float wB = out_W[r * HD + jB];
    pA0 += wA * (OA0[r] * iL0);
    pB0 += wB * (OB0[r] * iL0);
    pA1 += wA * (OA1[r] * iL1);
    pB1 += wB * (OB1[r] * iL1);
  }
  float* sred = &sh_gates[0][0];  // 8192 floats of scratch
  __syncthreads();
  sred[row * 256 + jA] = pA0;
  sred[row * 256 + jB] = pB0;
  sred[(row + 4) * 256 + jA] = pA1;
  sred[(row + 4) * 256 + jB] = pB1;
  __syncthreads();
  if (tid < RPB) {
    float acc = 0.f;
    for (int k = 0; k < 256; ++k) acc += sred[tid * 256 + k];
    float yh = acc + out_b[0];
    int b = b0 + tid;
    float lab = labels[b], tr = is_train[b];
    float bce = fmaxf(yh, 0.f) - yh * lab + log1pf(expf(-fabsf(yh)));
    atomicAdd(&ws[1], bce * tr);
    out[1 + b] = 1.f / (1.f + expf(-yh));
  }
  __syncthreads();
  sred[tid] = (float)lossAcc;
  __syncthreads();
  for (int off = 256; off > 0; off >>= 1) {
    if (tid < off) sred[tid] += sred[tid + off];
    __syncthreads();
  }
  if (tid == 0) atomicAdd(&ws[0], sred[0]);
}

__global__ void final_kernel(const float* __restrict__ ws, float* __restrict__ out) {
  if (threadIdx.x == 0 && blockIdx.x == 0) {
    out[0] = ws[0] / (float)SS + 0.1f * (ws[1] / (ws[2] + 1e-5f));
  }
}

extern "C" void kernel_launch(void* const* d_in, const int* in_sizes, int n_in,
                              void* d_out, int out_size, void* d_ws, size_t ws_size,
                              hipStream_t stream) {
  const float* values   = (const float*)d_in[0];
  const float* masks    = (const float*)d_in[1];
  const float* deltas   = (const float*)d_in[2];
  const float* labels   = (const float*)d_in[3];
  const float* is_train = (const float*)d_in[4];
  const float* td_h_W   = (const float*)d_in[5];
  const float* td_h_b   = (const float*)d_in[6];
  const float* td_x_W   = (const float*)d_in[7];
  const float* td_x_b   = (const float*)d_in[8];
  const float* hist_W   = (const float*)d_in[9];
  const float* hist_b   = (const float*)d_in[10];
  const float* feat_W   = (const float*)d_in[11];
  const float* feat_b   = (const float*)d_in[12];
  const float* comb_W   = (const float*)d_in[13];
  const float* comb_b   = (const float*)d_in[14];
  const float* W_ih     = (const float*)d_in[15];
  const float* b_ih     = (const float*)d_in[16];
  const float* W_hh     = (const float*)d_in[17];
  const float* b_hh     = (const float*)d_in[18];
  const float* Ws1_W    = (const float*)d_in[19];
  const float* Ws1_b    = (const float*)d_in[20];
  const float* Ws2_W    = (const float*)d_in[21];
  const float* Ws2_b    = (const float*)d_in[22];
  const float* out_W    = (const float*)d_in[23];
  const float* out_b    = (const float*)d_in[24];
  float* out = (float*)d_out;
  float* ws  = (float*)d_ws;

  short* b5 = (short*)((char*)d_ws + WS_B5_OFS);
  short* b6 = (short*)((char*)d_ws + WS_B6_OFS);
  short* b3 = (short*)((char*)d_ws + WS_B3_OFS);
  short* b2 = (short*)((char*)d_ws + WS_B2_OFS);
  short* b7 = (short*)((char*)d_ws + WS_B7_OFS);

  convert_weights<<<(CW_TOTAL + 255) / 256, 256, 0, stream>>>(
      W_ih, W_hh, Ws1_W, hist_W, td_h_W, Ws2_W, b5, b6, b3, b2, b7);
  prep_kernel<<<SS, 256, 0, stream>>>(masks, is_train, ws);
  rits_main<<<BB / RPB, 512, 0, stream>>>(
      values, masks, deltas, labels, is_train,
      td_h_b, td_x_W, td_x_b, hist_b, feat_W, feat_b, comb_W, comb_b,
      b_ih, b_hh, Ws1_b, Ws2_W, Ws2_b, out_W, out_b, out, ws);
  final_kernel<<<1, 64, 0, stream>>>(ws, out);
}

// Round 6
// 10140.946 us; speedup vs baseline: 1.8710x; 1.8710x over previous
//
#include <hip/hip_runtime.h>
#include <hip/hip_bf16.h>
#include <math.h>

// RITS-style RNN + late attention, fused persistent kernel. Round 9:
//  - Diagnosis: round-0 kernel is latency-serialized at 1 WG/CU (grid 256 =
//    CU count; 8 waves stall together at each of 8 barriers; MfmaUtil 7%,
//    VALUBusy 16%, L2 at ~33% of ceiling). RPB=8 axis abandoned: it does not
//    shorten the per-block serial chain (and kept spilling).
//  - Fix: RPB=2, 512 blocks -> 2 co-resident WGs per CU. Independent WGs
//    overlap each other's barrier drains (m114: MFMA wave + VALU wave on one
//    CU co-schedule fully). LDS ~32 KB (2 WGs fit under 160 KB); each thread
//    owns ONE h-unit (j = tid&255, row = tid>>8) so O-state is 30 regs;
//    VGPR ~100 under the (512,2) 128-cap that round-0 ran at spill-free.
//  - Everything else is the verified round-0 structure: serial phase 7,
//    b5/b6/b3/b2 converter, same phase order; writer guards r<2 instead of
//    r<4; + register prefetch of x/d/m and hoisted per-lane biases (both
//    correctness-verified in round 4).
// ws layout: f32 ws[0]=xl ws[1]=y ws[2]=tr_sum ws[16..272)=msum; then bf16
// B-frag tensors at WS_B5/B6/B3/B2 (~1.01 MB).

#define BB 1024
#define SS 256
#define NF 64
#define HD 256
#define DAA 350
#define DRR 30
#define RPB 2

#define WS_B5_OFS 4096
#define WS_B5_ELEMS (64 * 12 * 64 * 8)   // gates: 64 n-tiles x 12 k-tiles
#define WS_B6_OFS (WS_B5_OFS + WS_B5_ELEMS * 2)
#define WS_B6_ELEMS (22 * 8 * 64 * 8)    // Ws1: 22 n-tiles x 8 k-tiles
#define WS_B3_OFS (WS_B6_OFS + WS_B6_ELEMS * 2)
#define WS_B3_ELEMS (4 * 8 * 64 * 8)     // hist: 4 n-tiles x 8 k-tiles
#define WS_B2_OFS (WS_B3_OFS + WS_B3_ELEMS * 2)
#define WS_B2_ELEMS (16 * 2 * 64 * 8)    // td_h: 16 n-tiles x 2 k-tiles
#define CW_TOTAL (WS_B5_ELEMS + WS_B6_ELEMS + WS_B3_ELEMS + WS_B2_ELEMS)

typedef __attribute__((ext_vector_type(8))) short bf16x8;
typedef __attribute__((ext_vector_type(4))) float f32x4;

__device__ __forceinline__ float dot4f(float4 a, float4 b) {
  return fmaf(a.x, b.x, fmaf(a.y, b.y, fmaf(a.z, b.z, a.w * b.w)));
}

__device__ __forceinline__ short f2bs(float v) {
  __hip_bfloat16 t = __float2bfloat16(v);
  return *reinterpret_cast<short*>(&t);
}

__global__ __launch_bounds__(256) void convert_weights(
    const float* __restrict__ W_ih, const float* __restrict__ W_hh,
    const float* __restrict__ Ws1_W, const float* __restrict__ hist_W,
    const float* __restrict__ td_h_W,
    short* __restrict__ b5, short* __restrict__ b6,
    short* __restrict__ b3, short* __restrict__ b2)
{
  int idx = blockIdx.x * 256 + threadIdx.x;
  if (idx < WS_B5_ELEMS) {
    int j = idx & 7; int e8 = idx >> 3; int lane = e8 & 63; int tile = e8 >> 6;
    int kt = tile % 12, nt = tile / 12;
    int g = nt * 16 + (lane & 15);
    int k = kt * 32 + (lane >> 4) * 8 + j;  // [c_c(64)|m(64)|h(256)]
    float v = (k < 128) ? W_ih[g * 128 + k] : W_hh[g * 256 + (k - 128)];
    b5[idx] = f2bs(v);
  } else if (idx < WS_B5_ELEMS + WS_B6_ELEMS) {
    int i = idx - WS_B5_ELEMS;
    int j = i & 7; int e8 = i >> 3; int lane = e8 & 63; int tile = e8 >> 6;
    int kt = tile & 7, nt = tile >> 3;
    int a = nt * 16 + (lane & 15);
    int k = kt * 32 + (lane >> 4) * 8 + j;
    float v = (a < DAA) ? Ws1_W[a * 256 + k] : 0.f;
    b6[i] = f2bs(v);
  } else if (idx < WS_B5_ELEMS + WS_B6_ELEMS + WS_B3_ELEMS) {
    int i = idx - WS_B5_ELEMS - WS_B6_ELEMS;
    int j = i & 7; int e8 = i >> 3; int lane = e8 & 63; int tile = e8 >> 6;
    int kt = tile & 7, nt = tile >> 3;
    int n = nt * 16 + (lane & 15);
    int k = kt * 32 + (lane >> 4) * 8 + j;
    b3[i] = f2bs(hist_W[n * 256 + k]);
  } else if (idx < CW_TOTAL) {
    int i = idx - WS_B5_ELEMS - WS_B6_ELEMS - WS_B3_ELEMS;
    int j = i & 7; int e8 = i >> 3; int lane = e8 & 63; int tile = e8 >> 6;
    int kt = tile & 1, nt = tile >> 1;
    int g = nt * 16 + (lane & 15);
    int k = kt * 32 + (lane >> 4) * 8 + j;
    b2[i] = f2bs(td_h_W[g * 64 + k]);
  }
}

__global__ __launch_bounds__(256) void prep_kernel(
    const float* __restrict__ masks, const float* __restrict__ is_train,
    float* __restrict__ ws)
{
  __shared__ float red[256];
  const int t = blockIdx.x;
  const int tid = threadIdx.x;
  float s = 0.f;
  for (int idx = tid; idx < BB * NF; idx += 256) {
    int b = idx >> 6, n = idx & 63;
    s += masks[(size_t)b * (SS * NF) + (size_t)t * NF + n];
  }
  red[tid] = s;
  __syncthreads();
  for (int off = 128; off > 0; off >>= 1) {
    if (tid < off) red[tid] += red[tid + off];
    __syncthreads();
  }
  if (tid == 0) ws[16 + t] = red[0] + 1e-5f;
  if (blockIdx.x == 0) {
    __syncthreads();
    float ts = 0.f;
    for (int idx = tid; idx < BB; idx += 256) ts += is_train[idx];
    red[tid] = ts;
    __syncthreads();
    for (int off = 128; off > 0; off >>= 1) {
      if (tid < off) red[tid] += red[tid + off];
      __syncthreads();
    }
    if (tid == 0) { ws[2] = red[0]; ws[0] = 0.f; ws[1] = 0.f; }
  }
}

__global__ __launch_bounds__(512, 2) void rits_main(
    const float* __restrict__ values, const float* __restrict__ masks_g,
    const float* __restrict__ deltas, const float* __restrict__ labels,
    const float* __restrict__ is_train,
    const float* __restrict__ td_h_b, const float* __restrict__ td_x_W,
    const float* __restrict__ td_x_b, const float* __restrict__ hist_b,
    const float* __restrict__ feat_W, const float* __restrict__ feat_b,
    const float* __restrict__ comb_W, const float* __restrict__ comb_b,
    const float* __restrict__ b_ih, const float* __restrict__ b_hh,
    const float* __restrict__ Ws1_b,
    const float* __restrict__ Ws2_W, const float* __restrict__ Ws2_b,
    const float* __restrict__ out_W, const float* __restrict__ out_b,
    float* __restrict__ out, float* __restrict__ ws)
{
  __shared__ __align__(16) float sh_a[RPB][384];   // f32: [unused|m|h]
  __shared__ __align__(16) short sh_ab[16][392];   // bf16 [c_c|m|h], rows 2+ zero
  __shared__ __align__(16) short sh_db[16][72];    // bf16 d, rows 2+ zero
  __shared__ __align__(16) float sh_x[RPB][NF];
  __shared__ __align__(16) float sh_d[RPB][NF];
  __shared__ __align__(16) float sh_xc[RPB][NF];
  __shared__ __align__(16) float sh_gx[RPB][NF];
  __shared__ __align__(16) float sh_xh[RPB][NF];
  __shared__ __align__(16) float sh_gates[RPB][1024];
  __shared__ __align__(16) float sh_s1[RPB][352];
  __shared__ float sh_w[RPB][32];
  __shared__ float sh_scale[RPB][32];
  __shared__ float sh_M[RPB][32];
  __shared__ float sh_L[RPB][32];
  __shared__ float sh_msum;

  const int tid = threadIdx.x;
  const int b0 = blockIdx.x * RPB;
  const int wv = tid >> 6;       // wave 0..7
  const int lane = tid & 63;
  const int lm = lane & 15;      // m/n within MFMA tile
  const int lq = lane >> 4;      // quad
  const int row = tid >> 8;      // LSTM/attention row 0..1 (one h-unit/thread)
  const int j = tid & 255;       // h index 0..255
  const int rw2 = (tid >> 6) & 1; // staging/feature row for tid<128
  const int nn = tid & 63;

  const bf16x8* b5 = (const bf16x8*)((const char*)ws + WS_B5_OFS);
  const bf16x8* b6 = (const bf16x8*)((const char*)ws + WS_B6_OFS);
  const bf16x8* b3 = (const bf16x8*)((const char*)ws + WS_B3_OFS);
  const bf16x8* b2 = (const bf16x8*)((const char*)ws + WS_B2_OFS);

  // ---- init LDS
  for (int i = tid; i < 16 * 392; i += 512) (&sh_ab[0][0])[i] = 0;
  for (int i = tid; i < 16 * 72; i += 512) (&sh_db[0][0])[i] = 0;
  for (int i = tid; i < RPB * 384; i += 512) (&sh_a[0][0])[i] = 0.f;
  if (tid < RPB * 32) {
    int rr = tid >> 5, q = tid & 31;
    sh_M[rr][q] = -1e30f;
    sh_L[rr][q] = 0.f;
  }

  // per-thread cached scalars (nn-indexed, used by tid<128 paths)
  const float tdxw  = td_x_W[nn * NF + nn];
  const float tdxb  = td_x_b[nn];
  const float featb = feat_b[nn];
  const float featd = feat_W[nn * NF + nn];
  const float combb = comb_b[nn];
  // LSTM gate biases for this thread's h-unit j
  float bg[4];
  #pragma unroll
  for (int q = 0; q < 4; ++q) bg[q] = b_ih[q * 256 + j] + b_hh[q * 256 + j];

  // hoisted per-lane bias constants for MFMA writer lanes (lq==0)
  float thb[2];
  thb[0] = td_h_b[(wv * 2 + 0) * 16 + lm];
  thb[1] = td_h_b[(wv * 2 + 1) * 16 + lm];
  float hbv = 0.f;
  if (wv < 4) hbv = hist_b[wv * 16 + lm];
  float w1b[3] = {0.f, 0.f, 0.f};
  #pragma unroll
  for (int ii = 0; ii < 3; ++ii) {
    int nt = wv + 8 * ii;
    int a = nt * 16 + lm;
    if (nt < 22 && a < DAA) w1b[ii] = Ws1_b[a];
  }
  float w2bv = 0.f;
  if (tid < RPB * DRR) w2bv = Ws2_b[tid % DRR];

  float cc = 0.f;           // LSTM cell state for (row, j)
  float O[DRR];
  #pragma unroll
  for (int r = 0; r < DRR; ++r) O[r] = 0.f;
  double lossAcc = 0.0;

  // ---- prefetch t=0 inputs into registers
  float pv_a = 0.f, pv_b = 0.f, pv_msum = 0.f;
  if (tid < 128) {
    size_t g = (size_t)(b0 + rw2) * (SS * NF) + nn;
    pv_a = values[g];
    pv_b = deltas[g];
  } else if (tid < 256) {
    int q = tid - 128; int rw = (q >> 6) & 1, n2 = q & 63;
    size_t g = (size_t)(b0 + rw) * (SS * NF) + n2;
    pv_a = masks_g[g];
  }
  if (tid == 0) pv_msum = ws[16];

  __syncthreads();

  for (int t = 0; t < SS; ++t) {
    // ---- stage prefetched x,d (+bf16 d) / m (f32+bf16)
    if (tid < 128) {
      sh_x[rw2][nn] = pv_a;
      sh_d[rw2][nn] = pv_b;
      sh_db[rw2][nn] = f2bs(pv_b);
    } else if (tid < 256) {
      int q = tid - 128;
      int rw = (q >> 6) & 1, n2 = q & 63;
      sh_a[rw][64 + n2] = pv_a;
      sh_ab[rw][64 + n2] = f2bs(pv_a);
    }
    if (tid == 0) sh_msum = pv_msum;
    __syncthreads(); // S1

    // ---- issue next-step input loads; latency hides under phases 2..8
    if (t + 1 < SS) {
      if (tid < 128) {
        size_t g = (size_t)(b0 + rw2) * (SS * NF) + (size_t)(t + 1) * NF + nn;
        pv_a = values[g];
        pv_b = deltas[g];
      } else if (tid < 256) {
        int q = tid - 128; int rw = (q >> 6) & 1, n2 = q & 63;
        size_t g = (size_t)(b0 + rw) * (SS * NF) + (size_t)(t + 1) * NF + n2;
        pv_a = masks_g[g];
      }
      if (tid == 0) pv_msum = ws[16 + t + 1];
    }

    // ---- phase 2: gamma_h via MFMA (16 n-tiles over h); writers decay h.
    {
      bf16x8 dfr[2];
      #pragma unroll
      for (int kt = 0; kt < 2; ++kt)
        dfr[kt] = *(const bf16x8*)(&sh_db[lm][0] + kt * 32 + lq * 8);
      #pragma unroll
      for (int ntl = 0; ntl < 2; ++ntl) {
        int nt = wv * 2 + ntl;
        f32x4 acc = {0.f, 0.f, 0.f, 0.f};
        const bf16x8* bp = b2 + (size_t)(nt * 2) * 64 + lane;
        acc = __builtin_amdgcn_mfma_f32_16x16x32_bf16(dfr[0], bp[0], acc, 0, 0, 0);
        acc = __builtin_amdgcn_mfma_f32_16x16x32_bf16(dfr[1], bp[64], acc, 0, 0, 0);
        if (lq == 0) {
          int g = nt * 16 + lm;
          float bias = thb[ntl];
          #pragma unroll
          for (int r = 0; r < RPB; ++r) {
            float gam = expf(-fmaxf(acc[r] + bias, 0.f));
            float h = sh_a[r][128 + g] * gam;
            sh_a[r][128 + g] = h;
            sh_ab[r][128 + g] = f2bs(h);
          }
        }
      }
      if (tid < 128) {
        float v = sh_d[rw2][nn] * tdxw + tdxb;  // diag only
        sh_gx[rw2][nn] = expf(-fmaxf(v, 0.f));
      }
    }
    __syncthreads(); // S2

    // ---- phase 3: x_h = h @ hist_W^T + b via MFMA (waves 0-3, 1 tile each)
    if (wv < 4) {
      int nt = wv;
      f32x4 acc = {0.f, 0.f, 0.f, 0.f};
      const bf16x8* bp = b3 + (size_t)(nt * 8) * 64 + lane;
      #pragma unroll
      for (int kt = 0; kt < 8; ++kt) {
        bf16x8 a = *(const bf16x8*)(&sh_ab[lm][128] + kt * 32 + lq * 8);
        acc = __builtin_amdgcn_mfma_f32_16x16x32_bf16(a, bp[kt * 64], acc, 0, 0, 0);
      }
      if (lq == 0) {
        int n = nt * 16 + lm;
        float lterm = 0.f;
        #pragma unroll
        for (int r = 0; r < RPB; ++r) {
          float xh = acc[r] + hbv;
          sh_xh[r][n] = xh;
          float m = sh_a[r][64 + n], x = sh_x[r][n];
          sh_xc[r][n] = m * x + (1.f - m) * xh;
          lterm += fabsf(x - xh) * m;
        }
        lossAcc += (double)(lterm / sh_msum);
      }
    }
    __syncthreads(); // S3

    // ---- phase 4: z_h (zero-diag feat), alpha, c_h, c_c (f32 VALU, 128 thr)
    if (tid < 128) {
      const float4* xc4 = (const float4*)&sh_xc[rw2][0];
      const float4* gx4 = (const float4*)&sh_gx[rw2][0];
      const float4* mm4 = (const float4*)&sh_a[rw2][64];
      const float4* fW  = (const float4*)(feat_W + nn * NF);
      const float4* cW0 = (const float4*)(comb_W + nn * 2 * NF);
      const float4* cW1 = (const float4*)(comb_W + nn * 2 * NF + NF);
      float az = 0.f, aa = 0.f;
      #pragma unroll
      for (int k = 0; k < 16; ++k) {
        az += dot4f(xc4[k], fW[k]);
        aa += dot4f(gx4[k], cW0[k]);
        aa += dot4f(mm4[k], cW1[k]);
      }
      float xcn = sh_xc[rw2][nn];
      float zh = az - xcn * featd + featb;
      float alpha = aa + combb;
      float xh = sh_xh[rw2][nn];
      float chv = alpha * zh + (1.f - alpha) * xh;
      float m = sh_a[rw2][64 + nn], x = sh_x[rw2][nn];
      float ccv = m * x + (1.f - m) * chv;
      sh_ab[rw2][nn] = f2bs(ccv);
      out[1 + BB + ((size_t)(b0 + rw2) * SS + t) * NF + nn] = ccv;
      float lsum = (fabsf(x - zh) + fabsf(x - chv)) * m;
      lossAcc += (double)(lsum / sh_msum);
    }
    __syncthreads(); // S4

    // ---- phase 5: gates via MFMA. Wave wv owns n-tiles wv*8..wv*8+7.
    {
      bf16x8 afr[12];
      #pragma unroll
      for (int kt = 0; kt < 12; ++kt)
        afr[kt] = *(const bf16x8*)(&sh_ab[lm][0] + kt * 32 + lq * 8);
      #pragma unroll 2
      for (int ntl = 0; ntl < 8; ++ntl) {
        int nt = wv * 8 + ntl;
        f32x4 acc = {0.f, 0.f, 0.f, 0.f};
        const bf16x8* bp = b5 + (size_t)(nt * 12) * 64 + lane;
        #pragma unroll
        for (int kt = 0; kt < 12; ++kt)
          acc = __builtin_amdgcn_mfma_f32_16x16x32_bf16(afr[kt], bp[kt * 64], acc, 0, 0, 0);
        if (lq == 0) {
          int n = nt * 16 + lm;
          #pragma unroll
          for (int r = 0; r < RPB; ++r) sh_gates[r][n] = acc[r];
        }
      }
    }
    __syncthreads(); // S5

    // ---- LSTM state update: one h-unit per thread (row, j)
    float hn;
    {
      float gi = sh_gates[row][j] + bg[0];
      float gf = sh_gates[row][256 + j] + bg[1];
      float gg = sh_gates[row][512 + j] + bg[2];
      float go = sh_gates[row][768 + j] + bg[3];
      float ig = 1.f / (1.f + expf(-gi));
      float fg = 1.f / (1.f + expf(-gf));
      float og = 1.f / (1.f + expf(-go));
      cc = fg * cc + ig * tanhf(gg);
      hn = og * tanhf(cc);
      sh_a[row][128 + j] = hn;
      sh_ab[row][128 + j] = f2bs(hn);
    }
    __syncthreads(); // S6

    // ---- phase 6: s1 = tanh(h @ Ws1^T + b1) via MFMA (22 tiles)
    {
      bf16x8 hfr[8];
      #pragma unroll
      for (int kt = 0; kt < 8; ++kt)
        hfr[kt] = *(const bf16x8*)(&sh_ab[lm][128] + kt * 32 + lq * 8);
      #pragma unroll
      for (int ii = 0; ii < 3; ++ii) {
        int nt = wv + 8 * ii;
        if (nt < 22) {
          f32x4 acc = {0.f, 0.f, 0.f, 0.f};
          const bf16x8* bp = b6 + (size_t)(nt * 8) * 64 + lane;
          #pragma unroll
          for (int kt = 0; kt < 8; ++kt)
            acc = __builtin_amdgcn_mfma_f32_16x16x32_bf16(hfr[kt], bp[kt * 64], acc, 0, 0, 0);
          if (lq == 0) {
            int a = nt * 16 + lm;
            if (a < DAA) {
              float bias = w1b[ii];
              #pragma unroll
              for (int r = 0; r < RPB; ++r) sh_s1[r][a] = tanhf(acc[r] + bias);
            }
          }
        }
      }
    }
    __syncthreads(); // S7

    // ---- phase 7: scores (serial dot, 60 threads) + online-softmax state
    if (tid < RPB * DRR) {
      int rw = tid / DRR;
      int r = tid - rw * DRR;
      const float2* s2 = (const float2*)&sh_s1[rw][0];
      const float2* w2 = (const float2*)(Ws2_W + (size_t)r * DAA);
      float acc = 0.f;
      #pragma unroll 5
      for (int k = 0; k < 175; ++k) {
        float2 a = s2[k], b = w2[k];
        acc = fmaf(a.x, b.x, fmaf(a.y, b.y, acc));
      }
      float sc = acc + w2bv;
      float Mo = sh_M[rw][r];
      float Mn = fmaxf(Mo, sc);
      float scl = expf(Mo - Mn);
      float w = expf(sc - Mn);
      sh_M[rw][r] = Mn;
      sh_L[rw][r] = sh_L[rw][r] * scl + w;
      sh_scale[rw][r] = scl;
      sh_w[rw][r] = w;
    }
    __syncthreads(); // S8

    // ---- phase 8: O[r] = O[r]*scale + w*h (registers; LDS broadcast)
    #pragma unroll
    for (int r = 0; r < DRR; ++r) {
      float scl = sh_scale[row][r];
      float w = sh_w[row][r];
      O[r] = O[r] * scl + w * hn;
    }
  }

  // ---- finalize: y_h = out_W . (O/L), bce, predictions, loss reduce
  float p = 0.f;
  #pragma unroll
  for (int r = 0; r < DRR; ++r) {
    float invL = 1.f / sh_L[row][r];
    p += out_W[r * HD + j] * (O[r] * invL);
  }
  float* sred = &sh_gates[0][0];  // 2048 floats of scratch
  __syncthreads();
  sred[row * 256 + j] = p;
  __syncthreads();
  if (tid < RPB) {
    float acc = 0.f;
    for (int k = 0; k < 256; ++k) acc += sred[tid * 256 + k];
    float yh = acc + out_b[0];
    int b = b0 + tid;
    float lab = labels[b], tr = is_train[b];
    float bce = fmaxf(yh, 0.f) - yh * lab + log1pf(expf(-fabsf(yh)));
    atomicAdd(&ws[1], bce * tr);
    out[1 + b] = 1.f / (1.f + expf(-yh));
  }
  __syncthreads();
  sred[tid] = (float)lossAcc;
  __syncthreads();
  for (int off = 256; off > 0; off >>= 1) {
    if (tid < off) sred[tid] += sred[tid + off];
    __syncthreads();
  }
  if (tid == 0) atomicAdd(&ws[0], sred[0]);
}

__global__ void final_kernel(const float* __restrict__ ws, float* __restrict__ out) {
  if (threadIdx.x == 0 && blockIdx.x == 0) {
    out[0] = ws[0] / (float)SS + 0.1f * (ws[1] / (ws[2] + 1e-5f));
  }
}

extern "C" void kernel_launch(void* const* d_in, const int* in_sizes, int n_in,
                              void* d_out, int out_size, void* d_ws, size_t ws_size,
                              hipStream_t stream) {
  const float* values   = (const float*)d_in[0];
  const float* masks    = (const float*)d_in[1];
  const float* deltas   = (const float*)d_in[2];
  const float* labels   = (const float*)d_in[3];
  const float* is_train = (const float*)d_in[4];
  const float* td_h_W   = (const float*)d_in[5];
  const float* td_h_b   = (const float*)d_in[6];
  const float* td_x_W   = (const float*)d_in[7];
  const float* td_x_b   = (const float*)d_in[8];
  const float* hist_W   = (const float*)d_in[9];
  const float* hist_b   = (const float*)d_in[10];
  const float* feat_W   = (const float*)d_in[11];
  const float* feat_b   = (const float*)d_in[12];
  const float* comb_W   = (const float*)d_in[13];
  const float* comb_b   = (const float*)d_in[14];
  const float* W_ih     = (const float*)d_in[15];
  const float* b_ih     = (const float*)d_in[16];
  const float* W_hh     = (const float*)d_in[17];
  const float* b_hh     = (const float*)d_in[18];
  const float* Ws1_W    = (const float*)d_in[19];
  const float* Ws1_b    = (const float*)d_in[20];
  const float* Ws2_W    = (const float*)d_in[21];
  const float* Ws2_b    = (const float*)d_in[22];
  const float* out_W    = (const float*)d_in[23];
  const float* out_b    = (const float*)d_in[24];
  float* out = (float*)d_out;
  float* ws  = (float*)d_ws;

  short* b5 = (short*)((char*)d_ws + WS_B5_OFS);
  short* b6 = (short*)((char*)d_ws + WS_B6_OFS);
  short* b3 = (short*)((char*)d_ws + WS_B3_OFS);
  short* b2 = (short*)((char*)d_ws + WS_B2_OFS);

  convert_weights<<<(CW_TOTAL + 255) / 256, 256, 0, stream>>>(
      W_ih, W_hh, Ws1_W, hist_W, td_h_W, b5, b6, b3, b2);
  prep_kernel<<<SS, 256, 0, stream>>>(masks, is_train, ws);
  rits_main<<<BB / RPB, 512, 0, stream>>>(
      values, masks, deltas, labels, is_train,
      td_h_b, td_x_W, td_x_b, hist_b, feat_W, feat_b, comb_W, comb_b,
      b_ih, b_hh, Ws1_b, Ws2_W, Ws2_b, out_W, out_b, out, ws);
  final_kernel<<<1, 64, 0, stream>>>(ws, out);
}

// Round 7
// 4544.814 us; speedup vs baseline: 4.1747x; 2.2313x over previous
//
#include <hip/hip_runtime.h>
#include <hip/hip_bf16.h>
#include <math.h>

// RITS RNN + late attention. Round 10: DEFERRED ATTENTION.
//  - Evidence: per-block time is ~invariant in rows/block (5.07ms @RPB=2 vs
//    6.18ms @RPB=4) -> the scan is bound by the fixed per-step serial chain
//    (weight streaming through one CU's L2 port + 8 barrier latencies), and
//    co-residency of a second 512-thr WG does NOT happen (round-9 occupancy
//    stayed 24%). So: shorten the chain instead of widening the machine.
//  - h_t never feeds back into the recurrence -> phases 6-8 (b6 stream
//    360KB/step, serial scores, O-update, 3 barriers) leave the loop.
//    Scan kernel: phases 1-5 + LSTM, 5 barriers/step, writes h (bf16) to a
//    134MB H buffer in d_ws. Attention kernel: 1024 blocks (1 per batch row),
//    s1/scores/softmax/PV/y as batched MFMA GEMMs vs L3-resident H.
//  - ws_size guard: if d_ws can't hold H, run the verbatim round-0 fused
//    kernel (proven 6179us) instead -> no regression possible.
// ws: f32 ws[0]=xl ws[1]=y ws[2]=tr_sum ws[16..272)=msum; bf16 frags at
// WS_B5/B6/B3/B2/B7; bf16 H[1024][256][256] at WS_H_OFS (2MB).

#define BB 1024
#define SS 256
#define NF 64
#define HD 256
#define DAA 350
#define DRR 30
#define RPB 4

#define WS_B5_OFS 4096
#define WS_B5_ELEMS (64 * 12 * 64 * 8)
#define WS_B6_OFS (WS_B5_OFS + WS_B5_ELEMS * 2)
#define WS_B6_ELEMS (22 * 8 * 64 * 8)
#define WS_B3_OFS (WS_B6_OFS + WS_B6_ELEMS * 2)
#define WS_B3_ELEMS (4 * 8 * 64 * 8)
#define WS_B2_OFS (WS_B3_OFS + WS_B3_ELEMS * 2)
#define WS_B2_ELEMS (16 * 2 * 64 * 8)
#define WS_B7_OFS (WS_B2_OFS + WS_B2_ELEMS * 2)
#define WS_B7_ELEMS (2 * 11 * 64 * 8)
#define CW_TOTAL (WS_B5_ELEMS + WS_B6_ELEMS + WS_B3_ELEMS + WS_B2_ELEMS + WS_B7_ELEMS)
#define WS_H_OFS (2 * 1024 * 1024)
#define WS_H_BYTES ((size_t)BB * SS * HD * 2)

typedef __attribute__((ext_vector_type(8))) short bf16x8;
typedef __attribute__((ext_vector_type(4))) float f32x4;

__device__ __forceinline__ float dot4f(float4 a, float4 b) {
  return fmaf(a.x, b.x, fmaf(a.y, b.y, fmaf(a.z, b.z, a.w * b.w)));
}

__device__ __forceinline__ short f2bs(float v) {
  __hip_bfloat16 t = __float2bfloat16(v);
  return *reinterpret_cast<short*>(&t);
}

__global__ __launch_bounds__(256) void convert_weights(
    const float* __restrict__ W_ih, const float* __restrict__ W_hh,
    const float* __restrict__ Ws1_W, const float* __restrict__ hist_W,
    const float* __restrict__ td_h_W, const float* __restrict__ Ws2_W,
    short* __restrict__ b5, short* __restrict__ b6,
    short* __restrict__ b3, short* __restrict__ b2, short* __restrict__ b7)
{
  int idx = blockIdx.x * 256 + threadIdx.x;
  if (idx < WS_B5_ELEMS) {
    int j = idx & 7; int e8 = idx >> 3; int lane = e8 & 63; int tile = e8 >> 6;
    int kt = tile % 12, nt = tile / 12;
    int g = nt * 16 + (lane & 15);
    int k = kt * 32 + (lane >> 4) * 8 + j;  // [c_c(64)|m(64)|h(256)]
    float v = (k < 128) ? W_ih[g * 128 + k] : W_hh[g * 256 + (k - 128)];
    b5[idx] = f2bs(v);
  } else if (idx < WS_B5_ELEMS + WS_B6_ELEMS) {
    int i = idx - WS_B5_ELEMS;
    int j = i & 7; int e8 = i >> 3; int lane = e8 & 63; int tile = e8 >> 6;
    int kt = tile & 7, nt = tile >> 3;
    int a = nt * 16 + (lane & 15);
    int k = kt * 32 + (lane >> 4) * 8 + j;
    float v = (a < DAA) ? Ws1_W[a * 256 + k] : 0.f;
    b6[i] = f2bs(v);
  } else if (idx < WS_B5_ELEMS + WS_B6_ELEMS + WS_B3_ELEMS) {
    int i = idx - WS_B5_ELEMS - WS_B6_ELEMS;
    int j = i & 7; int e8 = i >> 3; int lane = e8 & 63; int tile = e8 >> 6;
    int kt = tile & 7, nt = tile >> 3;
    int n = nt * 16 + (lane & 15);
    int k = kt * 32 + (lane >> 4) * 8 + j;
    b3[i] = f2bs(hist_W[n * 256 + k]);
  } else if (idx < WS_B5_ELEMS + WS_B6_ELEMS + WS_B3_ELEMS + WS_B2_ELEMS) {
    int i = idx - WS_B5_ELEMS - WS_B6_ELEMS - WS_B3_ELEMS;
    int j = i & 7; int e8 = i >> 3; int lane = e8 & 63; int tile = e8 >> 6;
    int kt = tile & 1, nt = tile >> 1;
    int g = nt * 16 + (lane & 15);
    int k = kt * 32 + (lane >> 4) * 8 + j;
    b2[i] = f2bs(td_h_W[g * 64 + k]);
  } else if (idx < CW_TOTAL) {
    int i = idx - WS_B5_ELEMS - WS_B6_ELEMS - WS_B3_ELEMS - WS_B2_ELEMS;
    int j = i & 7; int e8 = i >> 3; int lane = e8 & 63; int tile = e8 >> 6;
    int kt = tile % 11, nt = tile / 11;
    int r = nt * 16 + (lane & 15);
    int k = kt * 32 + (lane >> 4) * 8 + j;
    float v = (r < DRR && k < DAA) ? Ws2_W[r * DAA + k] : 0.f;
    b7[i] = f2bs(v);
  }
}

__global__ __launch_bounds__(256) void prep_kernel(
    const float* __restrict__ masks, const float* __restrict__ is_train,
    float* __restrict__ ws)
{
  __shared__ float red[256];
  const int t = blockIdx.x;
  const int tid = threadIdx.x;
  float s = 0.f;
  for (int idx = tid; idx < BB * NF; idx += 256) {
    int b = idx >> 6, n = idx & 63;
    s += masks[(size_t)b * (SS * NF) + (size_t)t * NF + n];
  }
  red[tid] = s;
  __syncthreads();
  for (int off = 128; off > 0; off >>= 1) {
    if (tid < off) red[tid] += red[tid + off];
    __syncthreads();
  }
  if (tid == 0) ws[16 + t] = red[0] + 1e-5f;
  if (blockIdx.x == 0) {
    __syncthreads();
    float ts = 0.f;
    for (int idx = tid; idx < BB; idx += 256) ts += is_train[idx];
    red[tid] = ts;
    __syncthreads();
    for (int off = 128; off > 0; off >>= 1) {
      if (tid < off) red[tid] += red[tid + off];
      __syncthreads();
    }
    if (tid == 0) { ws[2] = red[0]; ws[0] = 0.f; ws[1] = 0.f; }
  }
}

// ---------------- scan kernel (phases 1-5 + LSTM; h -> ws H buffer) --------
__global__ __launch_bounds__(512, 2) void rits_scan(
    const float* __restrict__ values, const float* __restrict__ masks_g,
    const float* __restrict__ deltas,
    const float* __restrict__ td_h_b, const float* __restrict__ td_x_W,
    const float* __restrict__ td_x_b, const float* __restrict__ hist_b,
    const float* __restrict__ feat_W, const float* __restrict__ feat_b,
    const float* __restrict__ comb_W, const float* __restrict__ comb_b,
    const float* __restrict__ b_ih, const float* __restrict__ b_hh,
    float* __restrict__ out, float* __restrict__ ws)
{
  __shared__ __align__(16) float sh_a[RPB][384];   // f32: [unused|m|h]
  __shared__ __align__(16) short sh_ab[16][392];   // bf16 [c_c|m|h], rows 4+ zero
  __shared__ __align__(16) short sh_db[16][72];    // bf16 d, rows 4+ zero
  __shared__ __align__(16) float sh_x[RPB][NF];
  __shared__ __align__(16) float sh_d[RPB][NF];
  __shared__ __align__(16) float sh_xc[RPB][NF];
  __shared__ __align__(16) float sh_gx[RPB][NF];
  __shared__ __align__(16) float sh_xh[RPB][NF];
  __shared__ __align__(16) float sh_gates[RPB][1024];
  __shared__ float sh_msum;

  const int tid = threadIdx.x;
  const int b0 = blockIdx.x * RPB;
  const int wv = tid >> 6;
  const int lane = tid & 63;
  const int lm = lane & 15;
  const int lq = lane >> 4;
  const int row = tid >> 7;      // LSTM row 0..3
  const int j = tid & 127;
  const int jA = j, jB = j + 128;
  const int row2 = tid >> 6;     // staging row for tid<256
  const int nn = tid & 63;

  const bf16x8* b5 = (const bf16x8*)((const char*)ws + WS_B5_OFS);
  const bf16x8* b3 = (const bf16x8*)((const char*)ws + WS_B3_OFS);
  const bf16x8* b2 = (const bf16x8*)((const char*)ws + WS_B2_OFS);
  short* Hw = (short*)((char*)ws + WS_H_OFS);

  for (int i = tid; i < 16 * 392; i += 512) (&sh_ab[0][0])[i] = 0;
  for (int i = tid; i < 16 * 72; i += 512) (&sh_db[0][0])[i] = 0;
  for (int i = tid; i < RPB * 384; i += 512) (&sh_a[0][0])[i] = 0.f;

  const float tdxw  = td_x_W[nn * NF + nn];
  const float tdxb  = td_x_b[nn];
  const float featb = feat_b[nn];
  const float featd = feat_W[nn * NF + nn];
  const float combb = comb_b[nn];
  float bgA[4], bgB[4];
  #pragma unroll
  for (int q = 0; q < 4; ++q) {
    bgA[q] = b_ih[q * 256 + jA] + b_hh[q * 256 + jA];
    bgB[q] = b_ih[q * 256 + jB] + b_hh[q * 256 + jB];
  }
  float thb[2];
  thb[0] = td_h_b[(wv * 2 + 0) * 16 + lm];
  thb[1] = td_h_b[(wv * 2 + 1) * 16 + lm];
  float hbv = 0.f;
  if (wv < 4) hbv = hist_b[wv * 16 + lm];

  float cA = 0.f, cB = 0.f;
  double lossAcc = 0.0;

  // prefetch t=0
  float pv_a = 0.f, pv_b = 0.f, pv_msum = 0.f;
  if (tid < 256) {
    size_t g = (size_t)(b0 + row2) * (SS * NF) + nn;
    pv_a = values[g];
    pv_b = deltas[g];
  } else {
    int q = tid - 256; int rw = q >> 6, n2 = q & 63;
    size_t g = (size_t)(b0 + rw) * (SS * NF) + n2;
    pv_a = masks_g[g];
  }
  if (tid == 0) pv_msum = ws[16];

  __syncthreads();

  for (int t = 0; t < SS; ++t) {
    if (tid < 256) {
      sh_x[row2][nn] = pv_a;
      sh_d[row2][nn] = pv_b;
      sh_db[row2][nn] = f2bs(pv_b);
    } else {
      int q = tid - 256;
      int rw = q >> 6, n2 = q & 63;
      sh_a[rw][64 + n2] = pv_a;
      sh_ab[rw][64 + n2] = f2bs(pv_a);
    }
    if (tid == 0) sh_msum = pv_msum;
    __syncthreads(); // S1

    if (t + 1 < SS) {
      if (tid < 256) {
        size_t g = (size_t)(b0 + row2) * (SS * NF) + (size_t)(t + 1) * NF + nn;
        pv_a = values[g];
        pv_b = deltas[g];
      } else {
        int q = tid - 256; int rw = q >> 6, n2 = q & 63;
        size_t g = (size_t)(b0 + rw) * (SS * NF) + (size_t)(t + 1) * NF + n2;
        pv_a = masks_g[g];
      }
      if (tid == 0) pv_msum = ws[16 + t + 1];
    }

    // phase 2: gamma_h
    {
      bf16x8 dfr[2];
      #pragma unroll
      for (int kt = 0; kt < 2; ++kt)
        dfr[kt] = *(const bf16x8*)(&sh_db[lm][0] + kt * 32 + lq * 8);
      #pragma unroll
      for (int ntl = 0; ntl < 2; ++ntl) {
        int nt = wv * 2 + ntl;
        f32x4 acc = {0.f, 0.f, 0.f, 0.f};
        const bf16x8* bp = b2 + (size_t)(nt * 2) * 64 + lane;
        acc = __builtin_amdgcn_mfma_f32_16x16x32_bf16(dfr[0], bp[0], acc, 0, 0, 0);
        acc = __builtin_amdgcn_mfma_f32_16x16x32_bf16(dfr[1], bp[64], acc, 0, 0, 0);
        if (lq == 0) {
          int g = nt * 16 + lm;
          float bias = thb[ntl];
          #pragma unroll
          for (int r = 0; r < 4; ++r) {
            float gam = expf(-fmaxf(acc[r] + bias, 0.f));
            float h = sh_a[r][128 + g] * gam;
            sh_a[r][128 + g] = h;
            sh_ab[r][128 + g] = f2bs(h);
          }
        }
      }
      if (tid < 256) {
        float v = sh_d[row2][nn] * tdxw + tdxb;
        sh_gx[row2][nn] = expf(-fmaxf(v, 0.f));
      }
    }
    __syncthreads(); // S2

    // phase 3: x_h
    if (wv < 4) {
      int nt = wv;
      f32x4 acc = {0.f, 0.f, 0.f, 0.f};
      const bf16x8* bp = b3 + (size_t)(nt * 8) * 64 + lane;
      #pragma unroll
      for (int kt = 0; kt < 8; ++kt) {
        bf16x8 a = *(const bf16x8*)(&sh_ab[lm][128] + kt * 32 + lq * 8);
        acc = __builtin_amdgcn_mfma_f32_16x16x32_bf16(a, bp[kt * 64], acc, 0, 0, 0);
      }
      if (lq == 0) {
        int n = nt * 16 + lm;
        float lterm = 0.f;
        #pragma unroll
        for (int r = 0; r < 4; ++r) {
          float xh = acc[r] + hbv;
          sh_xh[r][n] = xh;
          float m = sh_a[r][64 + n], x = sh_x[r][n];
          sh_xc[r][n] = m * x + (1.f - m) * xh;
          lterm += fabsf(x - xh) * m;
        }
        lossAcc += (double)(lterm / sh_msum);
      }
    }
    __syncthreads(); // S3

    // phase 4
    if (tid < 256) {
      const float4* xc4 = (const float4*)&sh_xc[row2][0];
      const float4* gx4 = (const float4*)&sh_gx[row2][0];
      const float4* mm4 = (const float4*)&sh_a[row2][64];
      const float4* fW  = (const float4*)(feat_W + nn * NF);
      const float4* cW0 = (const float4*)(comb_W + nn * 2 * NF);
      const float4* cW1 = (const float4*)(comb_W + nn * 2 * NF + NF);
      float az = 0.f, aa = 0.f;
      #pragma unroll
      for (int k = 0; k < 16; ++k) {
        az += dot4f(xc4[k], fW[k]);
        aa += dot4f(gx4[k], cW0[k]);
        aa += dot4f(mm4[k], cW1[k]);
      }
      float xcn = sh_xc[row2][nn];
      float zh = az - xcn * featd + featb;
      float alpha = aa + combb;
      float xh = sh_xh[row2][nn];
      float chv = alpha * zh + (1.f - alpha) * xh;
      float m = sh_a[row2][64 + nn], x = sh_x[row2][nn];
      float ccv = m * x + (1.f - m) * chv;
      sh_ab[row2][nn] = f2bs(ccv);
      out[1 + BB + ((size_t)(b0 + row2) * SS + t) * NF + nn] = ccv;
      float lsum = (fabsf(x - zh) + fabsf(x - chv)) * m;
      lossAcc += (double)(lsum / sh_msum);
    }
    __syncthreads(); // S4

    // phase 5: gates
    {
      bf16x8 afr[12];
      #pragma unroll
      for (int kt = 0; kt < 12; ++kt)
        afr[kt] = *(const bf16x8*)(&sh_ab[lm][0] + kt * 32 + lq * 8);
      #pragma unroll 2
      for (int ntl = 0; ntl < 8; ++ntl) {
        int nt = wv * 8 + ntl;
        f32x4 acc = {0.f, 0.f, 0.f, 0.f};
        const bf16x8* bp = b5 + (size_t)(nt * 12) * 64 + lane;
        #pragma unroll
        for (int kt = 0; kt < 12; ++kt)
          acc = __builtin_amdgcn_mfma_f32_16x16x32_bf16(afr[kt], bp[kt * 64], acc, 0, 0, 0);
        if (lq == 0) {
          int n = nt * 16 + lm;
          #pragma unroll
          for (int r = 0; r < 4; ++r) sh_gates[r][n] = acc[r];
        }
      }
    }
    __syncthreads(); // S5

    // LSTM + h out (sh + global H buffer)
    {
      float giA = sh_gates[row][jA] + bgA[0];
      float gfA = sh_gates[row][256 + jA] + bgA[1];
      float ggA = sh_gates[row][512 + jA] + bgA[2];
      float goA = sh_gates[row][768 + jA] + bgA[3];
      float iA = 1.f / (1.f + expf(-giA));
      float fA = 1.f / (1.f + expf(-gfA));
      float oA = 1.f / (1.f + expf(-goA));
      cA = fA * cA + iA * tanhf(ggA);
      float hnA = oA * tanhf(cA);
      float giB = sh_gates[row][jB] + bgB[0];
      float gfB = sh_gates[row][256 + jB] + bgB[1];
      float ggB = sh_gates[row][512 + jB] + bgB[2];
      float goB = sh_gates[row][768 + jB] + bgB[3];
      float iB = 1.f / (1.f + expf(-giB));
      float fB = 1.f / (1.f + expf(-gfB));
      float oB = 1.f / (1.f + expf(-goB));
      cB = fB * cB + iB * tanhf(ggB);
      float hnB = oB * tanhf(cB);
      short hA = f2bs(hnA), hB = f2bs(hnB);
      sh_a[row][128 + jA] = hnA;
      sh_a[row][128 + jB] = hnB;
      sh_ab[row][128 + jA] = hA;
      sh_ab[row][128 + jB] = hB;
      size_t hb = ((size_t)(b0 + row) * SS + t) * HD;
      Hw[hb + jA] = hA;
      Hw[hb + jB] = hB;
    }
    // next-iteration S1 orders the h writes vs phase-2 reads
  }

  // loss reduce (x_loss only; y parts live in the attention kernel)
  float* sred = &sh_gates[0][0];
  __syncthreads();
  sred[tid] = (float)lossAcc;
  __syncthreads();
  for (int off = 256; off > 0; off >>= 1) {
    if (tid < off) sred[tid] += sred[tid + off];
    __syncthreads();
  }
  if (tid == 0) atomicAdd(&ws[0], sred[0]);
}

// ---------------- attention kernel: one block per batch row ----------------
__global__ __launch_bounds__(256) void rits_attn(
    const float* __restrict__ labels, const float* __restrict__ is_train,
    const float* __restrict__ Ws1_b,
    const float* __restrict__ out_W, const float* __restrict__ out_b,
    float* __restrict__ out, float* __restrict__ ws)
{
  __shared__ __align__(16) short sh_s1[16][360];  // bf16 s1 chunk, cols>=350 zero
  __shared__ __align__(16) float sh_sc[32][256];  // scoresT [r][s] f32 (rows 30,31 unused)
  __shared__ __align__(16) short sh_at[32][264];  // attn bf16 [r][s], rows 30,31 zero

  const int tid = threadIdx.x;
  const int b = blockIdx.x;
  const int wv = tid >> 6;       // wave 0..3
  const int lane = tid & 63;
  const int lm = lane & 15;
  const int lq = lane >> 4;

  const bf16x8* b6 = (const bf16x8*)((const char*)ws + WS_B6_OFS);
  const bf16x8* b7 = (const bf16x8*)((const char*)ws + WS_B7_OFS);
  const ushort* Hg = (const ushort*)((const char*)ws + WS_H_OFS) + (size_t)b * SS * HD;

  for (int i = tid; i < 16 * 360; i += 256) (&sh_s1[0][0])[i] = 0;
  for (int i = tid; i < 32 * 264; i += 256) (&sh_at[0][0])[i] = 0;

  // s1 writer biases: wave wv handles nt = wv + 4*i
  float w1b[6];
  #pragma unroll
  for (int i = 0; i < 6; ++i) {
    int nt = wv + 4 * i;
    int a = nt * 16 + lm;
    w1b[i] = (nt < 22 && a < DAA) ? Ws1_b[a] : 0.f;
  }
  __syncthreads();

  // ---- scores accumulation over 16-row s-chunks
  for (int sc0 = 0; sc0 < SS; sc0 += 16) {
    // A-frags: 16 H rows straight from global (L3-hot)
    bf16x8 afr[8];
    const ushort* Hrow = Hg + (size_t)(sc0 + lm) * HD;
    #pragma unroll
    for (int kt = 0; kt < 8; ++kt)
      afr[kt] = *(const bf16x8*)(Hrow + kt * 32 + lq * 8);
    // s1 = tanh(H . Ws1^T + b1) for this chunk
    int i = 0;
    for (int nt = wv; nt < 22; nt += 4, ++i) {
      f32x4 acc = {0.f, 0.f, 0.f, 0.f};
      const bf16x8* bp = b6 + (size_t)(nt * 8) * 64 + lane;
      #pragma unroll
      for (int kt = 0; kt < 8; ++kt)
        acc = __builtin_amdgcn_mfma_f32_16x16x32_bf16(afr[kt], bp[kt * 64], acc, 0, 0, 0);
      int a = nt * 16 + lm;
      if (a < DAA) {
        float bias = w1b[i];
        #pragma unroll
        for (int r = 0; r < 4; ++r)
          sh_s1[lq * 4 + r][a] = f2bs(tanhf(acc[r] + bias));
      }
    }
    __syncthreads();
    // scores chunk: [16 s] x [30 r] = s1 . Ws2^T  (waves 0-1)
    if (wv < 2) {
      bf16x8 s1f[11];
      #pragma unroll
      for (int kt = 0; kt < 11; ++kt)
        s1f[kt] = *(const bf16x8*)(&sh_s1[lm][0] + kt * 32 + lq * 8);
      f32x4 acc = {0.f, 0.f, 0.f, 0.f};
      const bf16x8* bp = b7 + (size_t)(wv * 11) * 64 + lane;
      #pragma unroll
      for (int kt = 0; kt < 11; ++kt)
        acc = __builtin_amdgcn_mfma_f32_16x16x32_bf16(s1f[kt], bp[kt * 64], acc, 0, 0, 0);
      int r = wv * 16 + lm;
      if (r < DRR) {
        // C: col=lane&15 -> r; row=lq*4+ri -> s_local. Ws2_b omitted (softmax
        // over s is shift-invariant in a per-r constant).
        float4 v = {acc[0], acc[1], acc[2], acc[3]};
        *(float4*)&sh_sc[r][sc0 + lq * 4] = v;
      }
    }
    __syncthreads();
  }

  // ---- softmax over s per r (8 threads per r)
  if (tid < 240) {
    int r = tid >> 3, g = tid & 7;
    float M = -1e30f;
    for (int s = g; s < SS; s += 8) M = fmaxf(M, sh_sc[r][s]);
    #pragma unroll
    for (int off = 1; off < 8; off <<= 1) M = fmaxf(M, __shfl_xor(M, off));
    float L = 0.f;
    for (int s = g; s < SS; s += 8) {
      float e = expf(sh_sc[r][s] - M);
      sh_sc[r][s] = e;
      L += e;
    }
    #pragma unroll
    for (int off = 1; off < 8; off <<= 1) L += __shfl_xor(L, off);
    float inv = 1.f / L;
    for (int s = g; s < SS; s += 8) sh_at[r][s] = f2bs(sh_sc[r][s] * inv);
  }
  __syncthreads();

  // ---- PV: hidden[r][h] = attn . H  (m=r 2 tiles, n=h: wave wv owns nt=wv*4+ntl)
  bf16x8 aat[2][8];
  #pragma unroll
  for (int mt = 0; mt < 2; ++mt)
    #pragma unroll
    for (int kt = 0; kt < 8; ++kt)
      aat[mt][kt] = *(const bf16x8*)(&sh_at[mt * 16 + lm][0] + kt * 32 + lq * 8);

  float p = 0.f;
  #pragma unroll
  for (int ntl = 0; ntl < 4; ++ntl) {
    int nt = wv * 4 + ntl;
    f32x4 acc0 = {0.f, 0.f, 0.f, 0.f};
    f32x4 acc1 = {0.f, 0.f, 0.f, 0.f};
    #pragma unroll
    for (int kt = 0; kt < 8; ++kt) {
      // B-frag gather from global H: B[k=s][n=h]
      const ushort* hp = Hg + (size_t)(kt * 32 + lq * 8) * HD + nt * 16 + lm;
      bf16x8 bf;
      #pragma unroll
      for (int jj = 0; jj < 8; ++jj) bf[jj] = (short)hp[(size_t)jj * HD];
      acc0 = __builtin_amdgcn_mfma_f32_16x16x32_bf16(aat[0][kt], bf, acc0, 0, 0, 0);
      acc1 = __builtin_amdgcn_mfma_f32_16x16x32_bf16(aat[1][kt], bf, acc1, 0, 0, 0);
    }
    int h = nt * 16 + lm;
    #pragma unroll
    for (int ri = 0; ri < 4; ++ri) {
      int r0 = lq * 4 + ri;
      p += out_W[r0 * HD + h] * acc0[ri];          // r0 < 16 always valid
      int r1 = 16 + lq * 4 + ri;
      if (r1 < DRR) p += out_W[r1 * HD + h] * acc1[ri];
    }
  }

  // ---- y reduce + bce + prediction
  float* sred = &sh_sc[0][0];
  __syncthreads();
  sred[tid] = p;
  __syncthreads();
  for (int off = 128; off > 0; off >>= 1) {
    if (tid < off) sred[tid] += sred[tid + off];
    __syncthreads();
  }
  if (tid == 0) {
    float yh = sred[0] + out_b[0];
    float lab = labels[b], tr = is_train[b];
    float bce = fmaxf(yh, 0.f) - yh * lab + log1pf(expf(-fabsf(yh)));
    atomicAdd(&ws[1], bce * tr);
    out[1 + b] = 1.f / (1.f + expf(-yh));
  }
}

// ---------------- fused fallback (verbatim round-0 kernel, 6179us) ---------
__global__ __launch_bounds__(512, 2) void rits_fused(
    const float* __restrict__ values, const float* __restrict__ masks_g,
    const float* __restrict__ deltas, const float* __restrict__ labels,
    const float* __restrict__ is_train,
    const float* __restrict__ td_h_b, const float* __restrict__ td_x_W,
    const float* __restrict__ td_x_b, const float* __restrict__ hist_b,
    const float* __restrict__ feat_W, const float* __restrict__ feat_b,
    const float* __restrict__ comb_W, const float* __restrict__ comb_b,
    const float* __restrict__ b_ih, const float* __restrict__ b_hh,
    const float* __restrict__ Ws1_b,
    const float* __restrict__ Ws2_W, const float* __restrict__ Ws2_b,
    const float* __restrict__ out_W, const float* __restrict__ out_b,
    float* __restrict__ out, float* __restrict__ ws)
{
  __shared__ __align__(16) float sh_a[4][384];
  __shared__ __align__(16) short sh_ab[16][392];
  __shared__ __align__(16) short sh_db[16][72];
  __shared__ __align__(16) float sh_x[4][NF];
  __shared__ __align__(16) float sh_d[4][NF];
  __shared__ __align__(16) float sh_xc[4][NF];
  __shared__ __align__(16) float sh_gx[4][NF];
  __shared__ __align__(16) float sh_xh[4][NF];
  __shared__ __align__(16) float sh_gates[4][1024];
  __shared__ __align__(16) float sh_s1[4][352];
  __shared__ float sh_w[4][32];
  __shared__ float sh_scale[4][32];
  __shared__ float sh_M[4][32];
  __shared__ float sh_L[4][32];
  __shared__ float sh_msum;

  const int tid = threadIdx.x;
  const int b0 = blockIdx.x * 4;
  const int wv = tid >> 6;
  const int lane = tid & 63;
  const int lm = lane & 15;
  const int lq = lane >> 4;
  const int row = tid >> 7;
  const int j = tid & 127;
  const int jA = j, jB = j + 128;
  const int row2 = tid >> 6;
  const int nn = tid & 63;

  const bf16x8* b5 = (const bf16x8*)((const char*)ws + WS_B5_OFS);
  const bf16x8* b6 = (const bf16x8*)((const char*)ws + WS_B6_OFS);
  const bf16x8* b3 = (const bf16x8*)((const char*)ws + WS_B3_OFS);
  const bf16x8* b2 = (const bf16x8*)((const char*)ws + WS_B2_OFS);

  for (int i = tid; i < 16 * 392; i += 512) (&sh_ab[0][0])[i] = 0;
  for (int i = tid; i < 16 * 72; i += 512) (&sh_db[0][0])[i] = 0;
  for (int i = tid; i < 4 * 384; i += 512) (&sh_a[0][0])[i] = 0.f;
  if (tid < 128) {
    int rr = tid >> 5, q = tid & 31;
    sh_M[rr][q] = -1e30f;
    sh_L[rr][q] = 0.f;
  }

  const float tdxw  = td_x_W[nn * NF + nn];
  const float tdxb  = td_x_b[nn];
  const float featb = feat_b[nn];
  const float featd = feat_W[nn * NF + nn];
  const float combb = comb_b[nn];
  float bgA[4], bgB[4];
  #pragma unroll
  for (int q = 0; q < 4; ++q) {
    bgA[q] = b_ih[q * 256 + jA] + b_hh[q * 256 + jA];
    bgB[q] = b_ih[q * 256 + jB] + b_hh[q * 256 + jB];
  }

  float cA = 0.f, cB = 0.f;
  float OA[DRR], OBv[DRR];
  #pragma unroll
  for (int r = 0; r < DRR; ++r) { OA[r] = 0.f; OBv[r] = 0.f; }
  double lossAcc = 0.0;

  __syncthreads();

  for (int t = 0; t < SS; ++t) {
    if (tid < 256) {
      size_t g = (size_t)(b0 + row2) * (SS * NF) + (size_t)t * NF + nn;
      float xv = values[g], dv = deltas[g];
      sh_x[row2][nn] = xv;
      sh_d[row2][nn] = dv;
      sh_db[row2][nn] = f2bs(dv);
    } else {
      int q = tid - 256;
      int rw = q >> 6, n2 = q & 63;
      size_t g = (size_t)(b0 + rw) * (SS * NF) + (size_t)t * NF + n2;
      float mv = masks_g[g];
      sh_a[rw][64 + n2] = mv;
      sh_ab[rw][64 + n2] = f2bs(mv);
    }
    if (tid == 0) sh_msum = ws[16 + t];
    __syncthreads();

    {
      bf16x8 dfr[2];
      #pragma unroll
      for (int kt = 0; kt < 2; ++kt)
        dfr[kt] = *(const bf16x8*)(&sh_db[lm][0] + kt * 32 + lq * 8);
      #pragma unroll
      for (int ntl = 0; ntl < 2; ++ntl) {
        int nt = wv * 2 + ntl;
        f32x4 acc = {0.f, 0.f, 0.f, 0.f};
        const bf16x8* bp = b2 + (size_t)(nt * 2) * 64 + lane;
        acc = __builtin_amdgcn_mfma_f32_16x16x32_bf16(dfr[0], bp[0], acc, 0, 0, 0);
        acc = __builtin_amdgcn_mfma_f32_16x16x32_bf16(dfr[1], bp[64], acc, 0, 0, 0);
        if (lq == 0) {
          int g = nt * 16 + lm;
          float bias = td_h_b[g];
          #pragma unroll
          for (int r = 0; r < 4; ++r) {
            float gam = expf(-fmaxf(acc[r] + bias, 0.f));
            float h = sh_a[r][128 + g] * gam;
            sh_a[r][128 + g] = h;
            sh_ab[r][128 + g] = f2bs(h);
          }
        }
      }
      if (tid < 256) {
        float v = sh_d[row2][nn] * tdxw + tdxb;
        sh_gx[row2][nn] = expf(-fmaxf(v, 0.f));
      }
    }
    __syncthreads();

    if (wv < 4) {
      int nt = wv;
      f32x4 acc = {0.f, 0.f, 0.f, 0.f};
      const bf16x8* bp = b3 + (size_t)(nt * 8) * 64 + lane;
      #pragma unroll
      for (int kt = 0; kt < 8; ++kt) {
        bf16x8 a = *(const bf16x8*)(&sh_ab[lm][128] + kt * 32 + lq * 8);
        acc = __builtin_amdgcn_mfma_f32_16x16x32_bf16(a, bp[kt * 64], acc, 0, 0, 0);
      }
      if (lq == 0) {
        int n = nt * 16 + lm;
        float bias = hist_b[n];
        float lterm = 0.f;
        #pragma unroll
        for (int r = 0; r < 4; ++r) {
          float xh = acc[r] + bias;
          sh_xh[r][n] = xh;
          float m = sh_a[r][64 + n], x = sh_x[r][n];
          sh_xc[r][n] = m * x + (1.f - m) * xh;
          lterm += fabsf(x - xh) * m;
        }
        lossAcc += (double)(lterm / sh_msum);
      }
    }
    __syncthreads();

    if (tid < 256) {
      const float4* xc4 = (const float4*)&sh_xc[row2][0];
      const float4* gx4 = (const float4*)&sh_gx[row2][0];
      const float4* mm4 = (const float4*)&sh_a[row2][64];
      const float4* fW  = (const float4*)(feat_W + nn * NF);
      const float4* cW0 = (const float4*)(comb_W + nn * 2 * NF);
      const float4* cW1 = (const float4*)(comb_W + nn * 2 * NF + NF);
      float az = 0.f, aa = 0.f;
      #pragma unroll
      for (int k = 0; k < 16; ++k) {
        az += dot4f(xc4[k], fW[k]);
        aa += dot4f(gx4[k], cW0[k]);
        aa += dot4f(mm4[k], cW1[k]);
      }
      float xcn = sh_xc[row2][nn];
      float zh = az - xcn * featd + featb;
      float alpha = aa + combb;
      float xh = sh_xh[row2][nn];
      float chv = alpha * zh + (1.f - alpha) * xh;
      float m = sh_a[row2][64 + nn], x = sh_x[row2][nn];
      float ccv = m * x + (1.f - m) * chv;
      sh_ab[row2][nn] = f2bs(ccv);
      out[1 + BB + ((size_t)(b0 + row2) * SS + t) * NF + nn] = ccv;
      float lsum = (fabsf(x - zh) + fabsf(x - chv)) * m;
      lossAcc += (double)(lsum / sh_msum);
    }
    __syncthreads();

    {
      bf16x8 afr[12];
      #pragma unroll
      for (int kt = 0; kt < 12; ++kt)
        afr[kt] = *(const bf16x8*)(&sh_ab[lm][0] + kt * 32 + lq * 8);
      #pragma unroll 2
      for (int ntl = 0; ntl < 8; ++ntl) {
        int nt = wv * 8 + ntl;
        f32x4 acc = {0.f, 0.f, 0.f, 0.f};
        const bf16x8* bp = b5 + (size_t)(nt * 12) * 64 + lane;
        #pragma unroll
        for (int kt = 0; kt < 12; ++kt)
          acc = __builtin_amdgcn_mfma_f32_16x16x32_bf16(afr[kt], bp[kt * 64], acc, 0, 0, 0);
        if (lq == 0) {
          int n = nt * 16 + lm;
          #pragma unroll
          for (int r = 0; r < 4; ++r) sh_gates[r][n] = acc[r];
        }
      }
    }
    __syncthreads();

    float hnA, hnB;
    {
      float giA = sh_gates[row][jA] + bgA[0];
      float gfA = sh_gates[row][256 + jA] + bgA[1];
      float ggA = sh_gates[row][512 + jA] + bgA[2];
      float goA = sh_gates[row][768 + jA] + bgA[3];
      float iA = 1.f / (1.f + expf(-giA));
      float fA = 1.f / (1.f + expf(-gfA));
      float oA = 1.f / (1.f + expf(-goA));
      cA = fA * cA + iA * tanhf(ggA);
      hnA = oA * tanhf(cA);
      float giB = sh_gates[row][jB] + bgB[0];
      float gfB = sh_gates[row][256 + jB] + bgB[1];
      float ggB = sh_gates[row][512 + jB] + bgB[2];
      float goB = sh_gates[row][768 + jB] + bgB[3];
      float iB = 1.f / (1.f + expf(-giB));
      float fB = 1.f / (1.f + expf(-gfB));
      float oB = 1.f / (1.f + expf(-goB));
      cB = fB * cB + iB * tanhf(ggB);
      hnB = oB * tanhf(cB);
      sh_a[row][128 + jA] = hnA;
      sh_a[row][128 + jB] = hnB;
      sh_ab[row][128 + jA] = f2bs(hnA);
      sh_ab[row][128 + jB] = f2bs(hnB);
    }
    __syncthreads();

    {
      bf16x8 hfr[8];
      #pragma unroll
      for (int kt = 0; kt < 8; ++kt)
        hfr[kt] = *(const bf16x8*)(&sh_ab[lm][128] + kt * 32 + lq * 8);
      for (int nt = wv; nt < 22; nt += 8) {
        f32x4 acc = {0.f, 0.f, 0.f, 0.f};
        const bf16x8* bp = b6 + (size_t)(nt * 8) * 64 + lane;
        #pragma unroll
        for (int kt = 0; kt < 8; ++kt)
          acc = __builtin_amdgcn_mfma_f32_16x16x32_bf16(hfr[kt], bp[kt * 64], acc, 0, 0, 0);
        if (lq == 0) {
          int a = nt * 16 + lm;
          if (a < DAA) {
            float bias = Ws1_b[a];
            #pragma unroll
            for (int r = 0; r < 4; ++r) sh_s1[r][a] = tanhf(acc[r] + bias);
          }
        }
      }
    }
    __syncthreads();

    if (tid < 4 * DRR) {
      int rw = tid / DRR;
      int r = tid - rw * DRR;
      const float2* s2 = (const float2*)&sh_s1[rw][0];
      const float2* w2 = (const float2*)(Ws2_W + (size_t)r * DAA);
      float acc = 0.f;
      #pragma unroll 5
      for (int k = 0; k < 175; ++k) {
        float2 a = s2[k], b = w2[k];
        acc = fmaf(a.x, b.x, fmaf(a.y, b.y, acc));
      }
      float sc = acc + Ws2_b[r];
      float Mo = sh_M[rw][r];
      float Mn = fmaxf(Mo, sc);
      float scl = expf(Mo - Mn);
      float w = expf(sc - Mn);
      sh_M[rw][r] = Mn;
      sh_L[rw][r] = sh_L[rw][r] * scl + w;
      sh_scale[rw][r] = scl;
      sh_w[rw][r] = w;
    }
    __syncthreads();

    #pragma unroll
    for (int r = 0; r < DRR; ++r) {
      float scl = sh_scale[row][r];
      float w = sh_w[row][r];
      OA[r]  = OA[r]  * scl + w * hnA;
      OBv[r] = OBv[r] * scl + w * hnB;
    }
  }

  float pA = 0.f, pB = 0.f;
  #pragma unroll
  for (int r = 0; r < DRR; ++r) {
    float invL = 1.f / sh_L[row][r];
    pA += out_W[r * HD + jA] * (OA[r]  * invL);
    pB += out_W[r * HD + jB] * (OBv[r] * invL);
  }
  float* sred = &sh_s1[0][0];
  __syncthreads();
  sred[row * 256 + jA] = pA;
  sred[row * 256 + jB] = pB;
  __syncthreads();
  if (tid < 4) {
    float acc = 0.f;
    for (int k = 0; k < 256; ++k) acc += sred[tid * 256 + k];
    float yh = acc + out_b[0];
    int b = b0 + tid;
    float lab = labels[b], tr = is_train[b];
    float bce = fmaxf(yh, 0.f) - yh * lab + log1pf(expf(-fabsf(yh)));
    atomicAdd(&ws[1], bce * tr);
    out[1 + b] = 1.f / (1.f + expf(-yh));
  }
  __syncthreads();
  sred[tid] = (float)lossAcc;
  __syncthreads();
  for (int off = 256; off > 0; off >>= 1) {
    if (tid < off) sred[tid] += sred[tid + off];
    __syncthreads();
  }
  if (tid == 0) atomicAdd(&ws[0], sred[0]);
}

__global__ void final_kernel(const float* __restrict__ ws, float* __restrict__ out) {
  if (threadIdx.x == 0 && blockIdx.x == 0) {
    out[0] = ws[0] / (float)SS + 0.1f * (ws[1] / (ws[2] + 1e-5f));
  }
}

extern "C" void kernel_launch(void* const* d_in, const int* in_sizes, int n_in,
                              void* d_out, int out_size, void* d_ws, size_t ws_size,
                              hipStream_t stream) {
  const float* values   = (const float*)d_in[0];
  const float* masks    = (const float*)d_in[1];
  const float* deltas   = (const float*)d_in[2];
  const float* labels   = (const float*)d_in[3];
  const float* is_train = (const float*)d_in[4];
  const float* td_h_W   = (const float*)d_in[5];
  const float* td_h_b   = (const float*)d_in[6];
  const float* td_x_W   = (const float*)d_in[7];
  const float* td_x_b   = (const float*)d_in[8];
  const float* hist_W   = (const float*)d_in[9];
  const float* hist_b   = (const float*)d_in[10];
  const float* feat_W   = (const float*)d_in[11];
  const float* feat_b   = (const float*)d_in[12];
  const float* comb_W   = (const float*)d_in[13];
  const float* comb_b   = (const float*)d_in[14];
  const float* W_ih     = (const float*)d_in[15];
  const float* b_ih     = (const float*)d_in[16];
  const float* W_hh     = (const float*)d_in[17];
  const float* b_hh     = (const float*)d_in[18];
  const float* Ws1_W    = (const float*)d_in[19];
  const float* Ws1_b    = (const float*)d_in[20];
  const float* Ws2_W    = (const float*)d_in[21];
  const float* Ws2_b    = (const float*)d_in[22];
  const float* out_W    = (const float*)d_in[23];
  const float* out_b    = (const float*)d_in[24];
  float* out = (float*)d_out;
  float* ws  = (float*)d_ws;

  short* b5 = (short*)((char*)d_ws + WS_B5_OFS);
  short* b6 = (short*)((char*)d_ws + WS_B6_OFS);
  short* b3 = (short*)((char*)d_ws + WS_B3_OFS);
  short* b2 = (short*)((char*)d_ws + WS_B2_OFS);
  short* b7 = (short*)((char*)d_ws + WS_B7_OFS);

  convert_weights<<<(CW_TOTAL + 255) / 256, 256, 0, stream>>>(
      W_ih, W_hh, Ws1_W, hist_W, td_h_W, Ws2_W, b5, b6, b3, b2, b7);
  prep_kernel<<<SS, 256, 0, stream>>>(masks, is_train, ws);

  if (ws_size >= (size_t)WS_H_OFS + WS_H_BYTES) {
    rits_scan<<<BB / RPB, 512, 0, stream>>>(
        values, masks, deltas,
        td_h_b, td_x_W, td_x_b, hist_b, feat_W, feat_b, comb_W, comb_b,
        b_ih, b_hh, out, ws);
    rits_attn<<<BB, 256, 0, stream>>>(
        labels, is_train, Ws1_b, out_W, out_b, out, ws);
  } else {
    rits_fused<<<BB / 4, 512, 0, stream>>>(
        values, masks, deltas, labels, is_train,
        td_h_b, td_x_W, td_x_b, hist_b, feat_W, feat_b, comb_W, comb_b,
        b_ih, b_hh, Ws1_b, Ws2_W, Ws2_b, out_W, out_b, out, ws);
  }
  final_kernel<<<1, 64, 0, stream>>>(ws, out);
}

// Round 8
// 4364.314 us; speedup vs baseline: 4.3474x; 1.0414x over previous
//
#include <hip/hip_runtime.h>
#include <hip/hip_bf16.h>
#include <math.h>

// RITS RNN + late attention. Round 11: 4-SEGMENT SCAN.
//  - Round-10 evidence: per-segment cost ~2.7us regardless of content (6
//    segments -> 16.3us/step; removing 3 saved 8us). The scan is bound by the
//    COUNT of barrier-separated dependency segments, not their work.
//  - gamma_h(t) depends only on d_t: compute gamma_h(t+1) in segment A of
//    step t (d prefetched 2 ahead into sh_db), store sh_gam; apply decay in
//    the LSTM segment as h_dec = h_new*gam. Phase-2 segment deleted.
//    gamma_x computed at stage time from the f32 prefetch register.
//  - Staging folded into the LSTM segment (one barrier serves both).
//  - Loop: A[x_h MFMA || gamma MFMA || prefetch] -> B[z_h/alpha/c_c] ->
//    C[gates MFMA] -> D[LSTM+decay+H+stage] : 4 barriers/step (was 6 seg).
//  - Deferred attention kernel + ws guard + round-0 fused fallback unchanged.
// ws: f32 ws[0]=xl ws[1]=y ws[2]=tr_sum ws[16..272)=msum; bf16 frags at
// WS_B5/B6/B3/B2/B7; bf16 H[1024][256][256] at WS_H_OFS.

#define BB 1024
#define SS 256
#define NF 64
#define HD 256
#define DAA 350
#define DRR 30
#define RPB 4

#define WS_B5_OFS 4096
#define WS_B5_ELEMS (64 * 12 * 64 * 8)
#define WS_B6_OFS (WS_B5_OFS + WS_B5_ELEMS * 2)
#define WS_B6_ELEMS (22 * 8 * 64 * 8)
#define WS_B3_OFS (WS_B6_OFS + WS_B6_ELEMS * 2)
#define WS_B3_ELEMS (4 * 8 * 64 * 8)
#define WS_B2_OFS (WS_B3_OFS + WS_B3_ELEMS * 2)
#define WS_B2_ELEMS (16 * 2 * 64 * 8)
#define WS_B7_OFS (WS_B2_OFS + WS_B2_ELEMS * 2)
#define WS_B7_ELEMS (2 * 11 * 64 * 8)
#define CW_TOTAL (WS_B5_ELEMS + WS_B6_ELEMS + WS_B3_ELEMS + WS_B2_ELEMS + WS_B7_ELEMS)
#define WS_H_OFS (2 * 1024 * 1024)
#define WS_H_BYTES ((size_t)BB * SS * HD * 2)

typedef __attribute__((ext_vector_type(8))) short bf16x8;
typedef __attribute__((ext_vector_type(4))) float f32x4;

__device__ __forceinline__ float dot4f(float4 a, float4 b) {
  return fmaf(a.x, b.x, fmaf(a.y, b.y, fmaf(a.z, b.z, a.w * b.w)));
}

__device__ __forceinline__ short f2bs(float v) {
  __hip_bfloat16 t = __float2bfloat16(v);
  return *reinterpret_cast<short*>(&t);
}

__global__ __launch_bounds__(256) void convert_weights(
    const float* __restrict__ W_ih, const float* __restrict__ W_hh,
    const float* __restrict__ Ws1_W, const float* __restrict__ hist_W,
    const float* __restrict__ td_h_W, const float* __restrict__ Ws2_W,
    short* __restrict__ b5, short* __restrict__ b6,
    short* __restrict__ b3, short* __restrict__ b2, short* __restrict__ b7)
{
  int idx = blockIdx.x * 256 + threadIdx.x;
  if (idx < WS_B5_ELEMS) {
    int j = idx & 7; int e8 = idx >> 3; int lane = e8 & 63; int tile = e8 >> 6;
    int kt = tile % 12, nt = tile / 12;
    int g = nt * 16 + (lane & 15);
    int k = kt * 32 + (lane >> 4) * 8 + j;  // [c_c(64)|m(64)|h(256)]
    float v = (k < 128) ? W_ih[g * 128 + k] : W_hh[g * 256 + (k - 128)];
    b5[idx] = f2bs(v);
  } else if (idx < WS_B5_ELEMS + WS_B6_ELEMS) {
    int i = idx - WS_B5_ELEMS;
    int j = i & 7; int e8 = i >> 3; int lane = e8 & 63; int tile = e8 >> 6;
    int kt = tile & 7, nt = tile >> 3;
    int a = nt * 16 + (lane & 15);
    int k = kt * 32 + (lane >> 4) * 8 + j;
    float v = (a < DAA) ? Ws1_W[a * 256 + k] : 0.f;
    b6[i] = f2bs(v);
  } else if (idx < WS_B5_ELEMS + WS_B6_ELEMS + WS_B3_ELEMS) {
    int i = idx - WS_B5_ELEMS - WS_B6_ELEMS;
    int j = i & 7; int e8 = i >> 3; int lane = e8 & 63; int tile = e8 >> 6;
    int kt = tile & 7, nt = tile >> 3;
    int n = nt * 16 + (lane & 15);
    int k = kt * 32 + (lane >> 4) * 8 + j;
    b3[i] = f2bs(hist_W[n * 256 + k]);
  } else if (idx < WS_B5_ELEMS + WS_B6_ELEMS + WS_B3_ELEMS + WS_B2_ELEMS) {
    int i = idx - WS_B5_ELEMS - WS_B6_ELEMS - WS_B3_ELEMS;
    int j = i & 7; int e8 = i >> 3; int lane = e8 & 63; int tile = e8 >> 6;
    int kt = tile & 1, nt = tile >> 1;
    int g = nt * 16 + (lane & 15);
    int k = kt * 32 + (lane >> 4) * 8 + j;
    b2[i] = f2bs(td_h_W[g * 64 + k]);
  } else if (idx < CW_TOTAL) {
    int i = idx - WS_B5_ELEMS - WS_B6_ELEMS - WS_B3_ELEMS - WS_B2_ELEMS;
    int j = i & 7; int e8 = i >> 3; int lane = e8 & 63; int tile = e8 >> 6;
    int kt = tile % 11, nt = tile / 11;
    int r = nt * 16 + (lane & 15);
    int k = kt * 32 + (lane >> 4) * 8 + j;
    float v = (r < DRR && k < DAA) ? Ws2_W[r * DAA + k] : 0.f;
    b7[i] = f2bs(v);
  }
}

__global__ __launch_bounds__(256) void prep_kernel(
    const float* __restrict__ masks, const float* __restrict__ is_train,
    float* __restrict__ ws)
{
  __shared__ float red[256];
  const int t = blockIdx.x;
  const int tid = threadIdx.x;
  float s = 0.f;
  for (int idx = tid; idx < BB * NF; idx += 256) {
    int b = idx >> 6, n = idx & 63;
    s += masks[(size_t)b * (SS * NF) + (size_t)t * NF + n];
  }
  red[tid] = s;
  __syncthreads();
  for (int off = 128; off > 0; off >>= 1) {
    if (tid < off) red[tid] += red[tid + off];
    __syncthreads();
  }
  if (tid == 0) ws[16 + t] = red[0] + 1e-5f;
  if (blockIdx.x == 0) {
    __syncthreads();
    float ts = 0.f;
    for (int idx = tid; idx < BB; idx += 256) ts += is_train[idx];
    red[tid] = ts;
    __syncthreads();
    for (int off = 128; off > 0; off >>= 1) {
      if (tid < off) red[tid] += red[tid + off];
      __syncthreads();
    }
    if (tid == 0) { ws[2] = red[0]; ws[0] = 0.f; ws[1] = 0.f; }
  }
}

// ---------------- scan kernel: 4 barrier segments per step -----------------
__global__ __launch_bounds__(512, 2) void rits_scan(
    const float* __restrict__ values, const float* __restrict__ masks_g,
    const float* __restrict__ deltas,
    const float* __restrict__ td_h_b, const float* __restrict__ td_x_W,
    const float* __restrict__ td_x_b, const float* __restrict__ hist_b,
    const float* __restrict__ feat_W, const float* __restrict__ feat_b,
    const float* __restrict__ comb_W, const float* __restrict__ comb_b,
    const float* __restrict__ b_ih, const float* __restrict__ b_hh,
    float* __restrict__ out, float* __restrict__ ws)
{
  __shared__ __align__(16) short sh_ab[16][392];   // bf16 [c_c|m|h_dec], rows 4+ zero
  __shared__ __align__(16) short sh_db[16][72];    // bf16 d_{t+1}, rows 4+ zero
  __shared__ __align__(16) float sh_x[RPB][NF];
  __shared__ __align__(16) float sh_m[RPB][NF];
  __shared__ __align__(16) float sh_xc[RPB][NF];
  __shared__ __align__(16) float sh_gx[RPB][NF];   // gamma_x(t)
  __shared__ __align__(16) float sh_xh[RPB][NF];
  __shared__ __align__(16) float sh_gam[RPB][HD];  // gamma_h(t+1) f32
  __shared__ __align__(16) float sh_gates[RPB][1024];
  __shared__ float sh_msum;

  const int tid = threadIdx.x;
  const int b0 = blockIdx.x * RPB;
  const int wv = tid >> 6;
  const int lane = tid & 63;
  const int lm = lane & 15;
  const int lq = lane >> 4;
  const int row = tid >> 7;      // LSTM row 0..3
  const int j = tid & 127;
  const int jA = j, jB = j + 128;
  const int row2 = tid >> 6;     // staging row for tid<256
  const int nn = tid & 63;

  const bf16x8* b5 = (const bf16x8*)((const char*)ws + WS_B5_OFS);
  const bf16x8* b3 = (const bf16x8*)((const char*)ws + WS_B3_OFS);
  const bf16x8* b2 = (const bf16x8*)((const char*)ws + WS_B2_OFS);
  short* Hw = (short*)((char*)ws + WS_H_OFS);

  for (int i = tid; i < 16 * 392; i += 512) (&sh_ab[0][0])[i] = 0;
  for (int i = tid; i < 16 * 72; i += 512) (&sh_db[0][0])[i] = 0;

  const float tdxw  = td_x_W[nn * NF + nn];
  const float tdxb  = td_x_b[nn];
  const float featb = feat_b[nn];
  const float featd = feat_W[nn * NF + nn];
  const float combb = comb_b[nn];
  float bgA[4], bgB[4];
  #pragma unroll
  for (int q = 0; q < 4; ++q) {
    bgA[q] = b_ih[q * 256 + jA] + b_hh[q * 256 + jA];
    bgB[q] = b_ih[q * 256 + jB] + b_hh[q * 256 + jB];
  }
  float thb[2];
  thb[0] = td_h_b[(wv * 2 + 0) * 16 + lm];
  thb[1] = td_h_b[(wv * 2 + 1) * 16 + lm];
  float hbv = 0.f;
  if (wv < 4) hbv = hist_b[wv * 16 + lm];

  float cA = 0.f, cB = 0.f;
  double lossAcc = 0.0;

  // ---- pre-loop: stage t=0 inputs, gamma_x(0), d_1 -> sh_db, msum(0)
  float pv_x = 0.f, pv_m = 0.f, pv_d2 = 0.f, pv_msum = 0.f;
  if (tid < 256) {
    size_t g = (size_t)(b0 + row2) * (SS * NF) + nn;
    sh_x[row2][nn] = values[g];
    float d0 = deltas[g];
    sh_gx[row2][nn] = expf(-fmaxf(d0 * tdxw + tdxb, 0.f));
    float d1 = deltas[g + NF];           // SS >= 2
    sh_db[row2][nn] = f2bs(d1);
    pv_d2 = d1;                           // becomes pv_d1 at A(0)
  } else {
    int q = tid - 256; int rw = q >> 6, n2 = q & 63;
    size_t g = (size_t)(b0 + rw) * (SS * NF) + n2;
    float mv = masks_g[g];
    sh_m[rw][n2] = mv;
    sh_ab[rw][64 + n2] = f2bs(mv);
  }
  if (tid == 0) sh_msum = ws[16];
  __syncthreads();

  for (int t = 0; t < SS; ++t) {
    // ================= Segment A =================
    // prefetch-issue for t+1 (x,m,msum) and t+2 (d)
    float pv_d1 = pv_d2;
    if (t + 1 < SS) {
      if (tid < 256) {
        size_t g = (size_t)(b0 + row2) * (SS * NF) + (size_t)(t + 1) * NF + nn;
        pv_x = values[g];
        if (t + 2 < SS) pv_d2 = deltas[g + NF];
      } else {
        int q = tid - 256; int rw = q >> 6, n2 = q & 63;
        size_t g = (size_t)(b0 + rw) * (SS * NF) + (size_t)(t + 1) * NF + n2;
        pv_m = masks_g[g];
      }
      if (tid == 0) pv_msum = ws[16 + t + 1];
    }

    // gamma_h(t+1) MFMA from sh_db (= d_{t+1}); all 8 waves, 2 tiles each
    {
      bf16x8 dfr[2];
      #pragma unroll
      for (int kt = 0; kt < 2; ++kt)
        dfr[kt] = *(const bf16x8*)(&sh_db[lm][0] + kt * 32 + lq * 8);
      #pragma unroll
      for (int ntl = 0; ntl < 2; ++ntl) {
        int nt = wv * 2 + ntl;
        f32x4 acc = {0.f, 0.f, 0.f, 0.f};
        const bf16x8* bp = b2 + (size_t)(nt * 2) * 64 + lane;
        acc = __builtin_amdgcn_mfma_f32_16x16x32_bf16(dfr[0], bp[0], acc, 0, 0, 0);
        acc = __builtin_amdgcn_mfma_f32_16x16x32_bf16(dfr[1], bp[64], acc, 0, 0, 0);
        if (lq == 0) {
          int g = nt * 16 + lm;
          float bias = thb[ntl];
          #pragma unroll
          for (int r = 0; r < 4; ++r)
            sh_gam[r][g] = expf(-fmaxf(acc[r] + bias, 0.f));
        }
      }
    }

    // x_h = h_dec @ hist^T (waves 0-3); writers: xh, xc, loss
    if (wv < 4) {
      int nt = wv;
      f32x4 acc = {0.f, 0.f, 0.f, 0.f};
      const bf16x8* bp = b3 + (size_t)(nt * 8) * 64 + lane;
      #pragma unroll
      for (int kt = 0; kt < 8; ++kt) {
        bf16x8 a = *(const bf16x8*)(&sh_ab[lm][128] + kt * 32 + lq * 8);
        acc = __builtin_amdgcn_mfma_f32_16x16x32_bf16(a, bp[kt * 64], acc, 0, 0, 0);
      }
      if (lq == 0) {
        int n = nt * 16 + lm;
        float lterm = 0.f;
        #pragma unroll
        for (int r = 0; r < 4; ++r) {
          float xh = acc[r] + hbv;
          sh_xh[r][n] = xh;
          float m = sh_m[r][n], x = sh_x[r][n];
          sh_xc[r][n] = m * x + (1.f - m) * xh;
          lterm += fabsf(x - xh) * m;
        }
        lossAcc += (double)(lterm / sh_msum);
      }
    }
    __syncthreads(); // SA

    // ================= Segment B =================
    if (tid < 256) {
      const float4* xc4 = (const float4*)&sh_xc[row2][0];
      const float4* gx4 = (const float4*)&sh_gx[row2][0];
      const float4* mm4 = (const float4*)&sh_m[row2][0];
      const float4* fW  = (const float4*)(feat_W + nn * NF);
      const float4* cW0 = (const float4*)(comb_W + nn * 2 * NF);
      const float4* cW1 = (const float4*)(comb_W + nn * 2 * NF + NF);
      float az = 0.f, aa = 0.f;
      #pragma unroll
      for (int k = 0; k < 16; ++k) {
        az += dot4f(xc4[k], fW[k]);
        aa += dot4f(gx4[k], cW0[k]);
        aa += dot4f(mm4[k], cW1[k]);
      }
      float xcn = sh_xc[row2][nn];
      float zh = az - xcn * featd + featb;
      float alpha = aa + combb;
      float xh = sh_xh[row2][nn];
      float chv = alpha * zh + (1.f - alpha) * xh;
      float m = sh_m[row2][nn], x = sh_x[row2][nn];
      float ccv = m * x + (1.f - m) * chv;
      sh_ab[row2][nn] = f2bs(ccv);
      out[1 + BB + ((size_t)(b0 + row2) * SS + t) * NF + nn] = ccv;
      float lsum = (fabsf(x - zh) + fabsf(x - chv)) * m;
      lossAcc += (double)(lsum / sh_msum);
    }
    __syncthreads(); // SB

    // ================= Segment C =================
    {
      bf16x8 afr[12];
      #pragma unroll
      for (int kt = 0; kt < 12; ++kt)
        afr[kt] = *(const bf16x8*)(&sh_ab[lm][0] + kt * 32 + lq * 8);
      #pragma unroll 2
      for (int ntl = 0; ntl < 8; ++ntl) {
        int nt = wv * 8 + ntl;
        f32x4 acc = {0.f, 0.f, 0.f, 0.f};
        const bf16x8* bp = b5 + (size_t)(nt * 12) * 64 + lane;
        #pragma unroll
        for (int kt = 0; kt < 12; ++kt)
          acc = __builtin_amdgcn_mfma_f32_16x16x32_bf16(afr[kt], bp[kt * 64], acc, 0, 0, 0);
        if (lq == 0) {
          int n = nt * 16 + lm;
          #pragma unroll
          for (int r = 0; r < 4; ++r) sh_gates[r][n] = acc[r];
        }
      }
    }
    __syncthreads(); // SC

    // ================= Segment D =================
    // LSTM update, decay with gamma_h(t+1), H write, stage t+1 inputs
    {
      float giA = sh_gates[row][jA] + bgA[0];
      float gfA = sh_gates[row][256 + jA] + bgA[1];
      float ggA = sh_gates[row][512 + jA] + bgA[2];
      float goA = sh_gates[row][768 + jA] + bgA[3];
      float iA = 1.f / (1.f + expf(-giA));
      float fA = 1.f / (1.f + expf(-gfA));
      float oA = 1.f / (1.f + expf(-goA));
      cA = fA * cA + iA * tanhf(ggA);
      float hnA = oA * tanhf(cA);
      float giB = sh_gates[row][jB] + bgB[0];
      float gfB = sh_gates[row][256 + jB] + bgB[1];
      float ggB = sh_gates[row][512 + jB] + bgB[2];
      float goB = sh_gates[row][768 + jB] + bgB[3];
      float iB = 1.f / (1.f + expf(-giB));
      float fB = 1.f / (1.f + expf(-gfB));
      float oB = 1.f / (1.f + expf(-goB));
      cB = fB * cB + iB * tanhf(ggB);
      float hnB = oB * tanhf(cB);
      // H buffer gets the UNdecayed h
      size_t hb = ((size_t)(b0 + row) * SS + t) * HD;
      Hw[hb + jA] = f2bs(hnA);
      Hw[hb + jB] = f2bs(hnB);
      // decayed h for next step's x_h/gates
      float hdA = hnA * sh_gam[row][jA];
      float hdB = hnB * sh_gam[row][jB];
      sh_ab[row][128 + jA] = f2bs(hdA);
      sh_ab[row][128 + jB] = f2bs(hdB);
    }
    if (t + 1 < SS) {
      if (tid < 256) {
        sh_x[row2][nn] = pv_x;
        sh_gx[row2][nn] = expf(-fmaxf(pv_d1 * tdxw + tdxb, 0.f)); // gamma_x(t+1)
        sh_db[row2][nn] = f2bs(pv_d2);                            // d_{t+2}
      } else {
        int q = tid - 256; int rw = q >> 6, n2 = q & 63;
        sh_m[rw][n2] = pv_m;
        sh_ab[rw][64 + n2] = f2bs(pv_m);
      }
      if (tid == 0) sh_msum = pv_msum;
    }
    __syncthreads(); // SD
  }

  // loss reduce (x_loss only)
  float* sred = &sh_gates[0][0];
  sred[tid] = (float)lossAcc;
  __syncthreads();
  for (int off = 256; off > 0; off >>= 1) {
    if (tid < off) sred[tid] += sred[tid + off];
    __syncthreads();
  }
  if (tid == 0) atomicAdd(&ws[0], sred[0]);
}

// ---------------- attention kernel: one block per batch row ----------------
__global__ __launch_bounds__(256) void rits_attn(
    const float* __restrict__ labels, const float* __restrict__ is_train,
    const float* __restrict__ Ws1_b,
    const float* __restrict__ out_W, const float* __restrict__ out_b,
    float* __restrict__ out, float* __restrict__ ws)
{
  __shared__ __align__(16) short sh_s1[16][360];  // bf16 s1 chunk, cols>=350 zero
  __shared__ __align__(16) float sh_sc[32][256];  // scoresT [r][s] f32
  __shared__ __align__(16) short sh_at[32][264];  // attn bf16 [r][s], rows 30,31 zero

  const int tid = threadIdx.x;
  const int b = blockIdx.x;
  const int wv = tid >> 6;       // wave 0..3
  const int lane = tid & 63;
  const int lm = lane & 15;
  const int lq = lane >> 4;

  const bf16x8* b6 = (const bf16x8*)((const char*)ws + WS_B6_OFS);
  const bf16x8* b7 = (const bf16x8*)((const char*)ws + WS_B7_OFS);
  const ushort* Hg = (const ushort*)((const char*)ws + WS_H_OFS) + (size_t)b * SS * HD;

  for (int i = tid; i < 16 * 360; i += 256) (&sh_s1[0][0])[i] = 0;
  for (int i = tid; i < 32 * 264; i += 256) (&sh_at[0][0])[i] = 0;

  float w1b[6];
  #pragma unroll
  for (int i = 0; i < 6; ++i) {
    int nt = wv + 4 * i;
    int a = nt * 16 + lm;
    w1b[i] = (nt < 22 && a < DAA) ? Ws1_b[a] : 0.f;
  }
  __syncthreads();

  for (int sc0 = 0; sc0 < SS; sc0 += 16) {
    bf16x8 afr[8];
    const ushort* Hrow = Hg + (size_t)(sc0 + lm) * HD;
    #pragma unroll
    for (int kt = 0; kt < 8; ++kt)
      afr[kt] = *(const bf16x8*)(Hrow + kt * 32 + lq * 8);
    int i = 0;
    for (int nt = wv; nt < 22; nt += 4, ++i) {
      f32x4 acc = {0.f, 0.f, 0.f, 0.f};
      const bf16x8* bp = b6 + (size_t)(nt * 8) * 64 + lane;
      #pragma unroll
      for (int kt = 0; kt < 8; ++kt)
        acc = __builtin_amdgcn_mfma_f32_16x16x32_bf16(afr[kt], bp[kt * 64], acc, 0, 0, 0);
      int a = nt * 16 + lm;
      if (a < DAA) {
        float bias = w1b[i];
        #pragma unroll
        for (int r = 0; r < 4; ++r)
          sh_s1[lq * 4 + r][a] = f2bs(tanhf(acc[r] + bias));
      }
    }
    __syncthreads();
    if (wv < 2) {
      bf16x8 s1f[11];
      #pragma unroll
      for (int kt = 0; kt < 11; ++kt)
        s1f[kt] = *(const bf16x8*)(&sh_s1[lm][0] + kt * 32 + lq * 8);
      f32x4 acc = {0.f, 0.f, 0.f, 0.f};
      const bf16x8* bp = b7 + (size_t)(wv * 11) * 64 + lane;
      #pragma unroll
      for (int kt = 0; kt < 11; ++kt)
        acc = __builtin_amdgcn_mfma_f32_16x16x32_bf16(s1f[kt], bp[kt * 64], acc, 0, 0, 0);
      int r = wv * 16 + lm;
      if (r < DRR) {
        float4 v = {acc[0], acc[1], acc[2], acc[3]};
        *(float4*)&sh_sc[r][sc0 + lq * 4] = v;
      }
    }
    __syncthreads();
  }

  if (tid < 240) {
    int r = tid >> 3, g = tid & 7;
    float M = -1e30f;
    for (int s = g; s < SS; s += 8) M = fmaxf(M, sh_sc[r][s]);
    #pragma unroll
    for (int off = 1; off < 8; off <<= 1) M = fmaxf(M, __shfl_xor(M, off));
    float L = 0.f;
    for (int s = g; s < SS; s += 8) {
      float e = expf(sh_sc[r][s] - M);
      sh_sc[r][s] = e;
      L += e;
    }
    #pragma unroll
    for (int off = 1; off < 8; off <<= 1) L += __shfl_xor(L, off);
    float inv = 1.f / L;
    for (int s = g; s < SS; s += 8) sh_at[r][s] = f2bs(sh_sc[r][s] * inv);
  }
  __syncthreads();

  bf16x8 aat[2][8];
  #pragma unroll
  for (int mt = 0; mt < 2; ++mt)
    #pragma unroll
    for (int kt = 0; kt < 8; ++kt)
      aat[mt][kt] = *(const bf16x8*)(&sh_at[mt * 16 + lm][0] + kt * 32 + lq * 8);

  float p = 0.f;
  #pragma unroll
  for (int ntl = 0; ntl < 4; ++ntl) {
    int nt = wv * 4 + ntl;
    f32x4 acc0 = {0.f, 0.f, 0.f, 0.f};
    f32x4 acc1 = {0.f, 0.f, 0.f, 0.f};
    #pragma unroll
    for (int kt = 0; kt < 8; ++kt) {
      const ushort* hp = Hg + (size_t)(kt * 32 + lq * 8) * HD + nt * 16 + lm;
      bf16x8 bf;
      #pragma unroll
      for (int jj = 0; jj < 8; ++jj) bf[jj] = (short)hp[(size_t)jj * HD];
      acc0 = __builtin_amdgcn_mfma_f32_16x16x32_bf16(aat[0][kt], bf, acc0, 0, 0, 0);
      acc1 = __builtin_amdgcn_mfma_f32_16x16x32_bf16(aat[1][kt], bf, acc1, 0, 0, 0);
    }
    int h = nt * 16 + lm;
    #pragma unroll
    for (int ri = 0; ri < 4; ++ri) {
      int r0 = lq * 4 + ri;
      p += out_W[r0 * HD + h] * acc0[ri];
      int r1 = 16 + lq * 4 + ri;
      if (r1 < DRR) p += out_W[r1 * HD + h] * acc1[ri];
    }
  }

  float* sred = &sh_sc[0][0];
  __syncthreads();
  sred[tid] = p;
  __syncthreads();
  for (int off = 128; off > 0; off >>= 1) {
    if (tid < off) sred[tid] += sred[tid + off];
    __syncthreads();
  }
  if (tid == 0) {
    float yh = sred[0] + out_b[0];
    float lab = labels[b], tr = is_train[b];
    float bce = fmaxf(yh, 0.f) - yh * lab + log1pf(expf(-fabsf(yh)));
    atomicAdd(&ws[1], bce * tr);
    out[1 + b] = 1.f / (1.f + expf(-yh));
  }
}

// ---------------- fused fallback (verbatim round-0 kernel, 6179us) ---------
__global__ __launch_bounds__(512, 2) void rits_fused(
    const float* __restrict__ values, const float* __restrict__ masks_g,
    const float* __restrict__ deltas, const float* __restrict__ labels,
    const float* __restrict__ is_train,
    const float* __restrict__ td_h_b, const float* __restrict__ td_x_W,
    const float* __restrict__ td_x_b, const float* __restrict__ hist_b,
    const float* __restrict__ feat_W, const float* __restrict__ feat_b,
    const float* __restrict__ comb_W, const float* __restrict__ comb_b,
    const float* __restrict__ b_ih, const float* __restrict__ b_hh,
    const float* __restrict__ Ws1_b,
    const float* __restrict__ Ws2_W, const float* __restrict__ Ws2_b,
    const float* __restrict__ out_W, const float* __restrict__ out_b,
    float* __restrict__ out, float* __restrict__ ws)
{
  __shared__ __align__(16) float sh_a[4][384];
  __shared__ __align__(16) short sh_ab[16][392];
  __shared__ __align__(16) short sh_db[16][72];
  __shared__ __align__(16) float sh_x[4][NF];
  __shared__ __align__(16) float sh_d[4][NF];
  __shared__ __align__(16) float sh_xc[4][NF];
  __shared__ __align__(16) float sh_gx[4][NF];
  __shared__ __align__(16) float sh_xh[4][NF];
  __shared__ __align__(16) float sh_gates[4][1024];
  __shared__ __align__(16) float sh_s1[4][352];
  __shared__ float sh_w[4][32];
  __shared__ float sh_scale[4][32];
  __shared__ float sh_M[4][32];
  __shared__ float sh_L[4][32];
  __shared__ float sh_msum;

  const int tid = threadIdx.x;
  const int b0 = blockIdx.x * 4;
  const int wv = tid >> 6;
  const int lane = tid & 63;
  const int lm = lane & 15;
  const int lq = lane >> 4;
  const int row = tid >> 7;
  const int j = tid & 127;
  const int jA = j, jB = j + 128;
  const int row2 = tid >> 6;
  const int nn = tid & 63;

  const bf16x8* b5 = (const bf16x8*)((const char*)ws + WS_B5_OFS);
  const bf16x8* b6 = (const bf16x8*)((const char*)ws + WS_B6_OFS);
  const bf16x8* b3 = (const bf16x8*)((const char*)ws + WS_B3_OFS);
  const bf16x8* b2 = (const bf16x8*)((const char*)ws + WS_B2_OFS);

  for (int i = tid; i < 16 * 392; i += 512) (&sh_ab[0][0])[i] = 0;
  for (int i = tid; i < 16 * 72; i += 512) (&sh_db[0][0])[i] = 0;
  for (int i = tid; i < 4 * 384; i += 512) (&sh_a[0][0])[i] = 0.f;
  if (tid < 128) {
    int rr = tid >> 5, q = tid & 31;
    sh_M[rr][q] = -1e30f;
    sh_L[rr][q] = 0.f;
  }

  const float tdxw  = td_x_W[nn * NF + nn];
  const float tdxb  = td_x_b[nn];
  const float featb = feat_b[nn];
  const float featd = feat_W[nn * NF + nn];
  const float combb = comb_b[nn];
  float bgA[4], bgB[4];
  #pragma unroll
  for (int q = 0; q < 4; ++q) {
    bgA[q] = b_ih[q * 256 + jA] + b_hh[q * 256 + jA];
    bgB[q] = b_ih[q * 256 + jB] + b_hh[q * 256 + jB];
  }

  float cA = 0.f, cB = 0.f;
  float OA[DRR], OBv[DRR];
  #pragma unroll
  for (int r = 0; r < DRR; ++r) { OA[r] = 0.f; OBv[r] = 0.f; }
  double lossAcc = 0.0;

  __syncthreads();

  for (int t = 0; t < SS; ++t) {
    if (tid < 256) {
      size_t g = (size_t)(b0 + row2) * (SS * NF) + (size_t)t * NF + nn;
      float xv = values[g], dv = deltas[g];
      sh_x[row2][nn] = xv;
      sh_d[row2][nn] = dv;
      sh_db[row2][nn] = f2bs(dv);
    } else {
      int q = tid - 256;
      int rw = q >> 6, n2 = q & 63;
      size_t g = (size_t)(b0 + rw) * (SS * NF) + (size_t)t * NF + n2;
      float mv = masks_g[g];
      sh_a[rw][64 + n2] = mv;
      sh_ab[rw][64 + n2] = f2bs(mv);
    }
    if (tid == 0) sh_msum = ws[16 + t];
    __syncthreads();

    {
      bf16x8 dfr[2];
      #pragma unroll
      for (int kt = 0; kt < 2; ++kt)
        dfr[kt] = *(const bf16x8*)(&sh_db[lm][0] + kt * 32 + lq * 8);
      #pragma unroll
      for (int ntl = 0; ntl < 2; ++ntl) {
        int nt = wv * 2 + ntl;
        f32x4 acc = {0.f, 0.f, 0.f, 0.f};
        const bf16x8* bp = b2 + (size_t)(nt * 2) * 64 + lane;
        acc = __builtin_amdgcn_mfma_f32_16x16x32_bf16(dfr[0], bp[0], acc, 0, 0, 0);
        acc = __builtin_amdgcn_mfma_f32_16x16x32_bf16(dfr[1], bp[64], acc, 0, 0, 0);
        if (lq == 0) {
          int g = nt * 16 + lm;
          float bias = td_h_b[g];
          #pragma unroll
          for (int r = 0; r < 4; ++r) {
            float gam = expf(-fmaxf(acc[r] + bias, 0.f));
            float h = sh_a[r][128 + g] * gam;
            sh_a[r][128 + g] = h;
            sh_ab[r][128 + g] = f2bs(h);
          }
        }
      }
      if (tid < 256) {
        float v = sh_d[row2][nn] * tdxw + tdxb;
        sh_gx[row2][nn] = expf(-fmaxf(v, 0.f));
      }
    }
    __syncthreads();

    if (wv < 4) {
      int nt = wv;
      f32x4 acc = {0.f, 0.f, 0.f, 0.f};
      const bf16x8* bp = b3 + (size_t)(nt * 8) * 64 + lane;
      #pragma unroll
      for (int kt = 0; kt < 8; ++kt) {
        bf16x8 a = *(const bf16x8*)(&sh_ab[lm][128] + kt * 32 + lq * 8);
        acc = __builtin_amdgcn_mfma_f32_16x16x32_bf16(a, bp[kt * 64], acc, 0, 0, 0);
      }
      if (lq == 0) {
        int n = nt * 16 + lm;
        float bias = hist_b[n];
        float lterm = 0.f;
        #pragma unroll
        for (int r = 0; r < 4; ++r) {
          float xh = acc[r] + bias;
          sh_xh[r][n] = xh;
          float m = sh_a[r][64 + n], x = sh_x[r][n];
          sh_xc[r][n] = m * x + (1.f - m) * xh;
          lterm += fabsf(x - xh) * m;
        }
        lossAcc += (double)(lterm / sh_msum);
      }
    }
    __syncthreads();

    if (tid < 256) {
      const float4* xc4 = (const float4*)&sh_xc[row2][0];
      const float4* gx4 = (const float4*)&sh_gx[row2][0];
      const float4* mm4 = (const float4*)&sh_a[row2][64];
      const float4* fW  = (const float4*)(feat_W + nn * NF);
      const float4* cW0 = (const float4*)(comb_W + nn * 2 * NF);
      const float4* cW1 = (const float4*)(comb_W + nn * 2 * NF + NF);
      float az = 0.f, aa = 0.f;
      #pragma unroll
      for (int k = 0; k < 16; ++k) {
        az += dot4f(xc4[k], fW[k]);
        aa += dot4f(gx4[k], cW0[k]);
        aa += dot4f(mm4[k], cW1[k]);
      }
      float xcn = sh_xc[row2][nn];
      float zh = az - xcn * featd + featb;
      float alpha = aa + combb;
      float xh = sh_xh[row2][nn];
      float chv = alpha * zh + (1.f - alpha) * xh;
      float m = sh_a[row2][64 + nn], x = sh_x[row2][nn];
      float ccv = m * x + (1.f - m) * chv;
      sh_ab[row2][nn] = f2bs(ccv);
      out[1 + BB + ((size_t)(b0 + row2) * SS + t) * NF + nn] = ccv;
      float lsum = (fabsf(x - zh) + fabsf(x - chv)) * m;
      lossAcc += (double)(lsum / sh_msum);
    }
    __syncthreads();

    {
      bf16x8 afr[12];
      #pragma unroll
      for (int kt = 0; kt < 12; ++kt)
        afr[kt] = *(const bf16x8*)(&sh_ab[lm][0] + kt * 32 + lq * 8);
      #pragma unroll 2
      for (int ntl = 0; ntl < 8; ++ntl) {
        int nt = wv * 8 + ntl;
        f32x4 acc = {0.f, 0.f, 0.f, 0.f};
        const bf16x8* bp = b5 + (size_t)(nt * 12) * 64 + lane;
        #pragma unroll
        for (int kt = 0; kt < 12; ++kt)
          acc = __builtin_amdgcn_mfma_f32_16x16x32_bf16(afr[kt], bp[kt * 64], acc, 0, 0, 0);
        if (lq == 0) {
          int n = nt * 16 + lm;
          #pragma unroll
          for (int r = 0; r < 4; ++r) sh_gates[r][n] = acc[r];
        }
      }
    }
    __syncthreads();

    float hnA, hnB;
    {
      float giA = sh_gates[row][jA] + bgA[0];
      float gfA = sh_gates[row][256 + jA] + bgA[1];
      float ggA = sh_gates[row][512 + jA] + bgA[2];
      float goA = sh_gates[row][768 + jA] + bgA[3];
      float iA = 1.f / (1.f + expf(-giA));
      float fA = 1.f / (1.f + expf(-gfA));
      float oA = 1.f / (1.f + expf(-goA));
      cA = fA * cA + iA * tanhf(ggA);
      hnA = oA * tanhf(cA);
      float giB = sh_gates[row][jB] + bgB[0];
      float gfB = sh_gates[row][256 + jB] + bgB[1];
      float ggB = sh_gates[row][512 + jB] + bgB[2];
      float goB = sh_gates[row][768 + jB] + bgB[3];
      float iB = 1.f / (1.f + expf(-giB));
      float fB = 1.f / (1.f + expf(-gfB));
      float oB = 1.f / (1.f + expf(-goB));
      cB = fB * cB + iB * tanhf(ggB);
      hnB = oB * tanhf(cB);
      sh_a[row][128 + jA] = hnA;
      sh_a[row][128 + jB] = hnB;
      sh_ab[row][128 + jA] = f2bs(hnA);
      sh_ab[row][128 + jB] = f2bs(hnB);
    }
    __syncthreads();

    {
      bf16x8 hfr[8];
      #pragma unroll
      for (int kt = 0; kt < 8; ++kt)
        hfr[kt] = *(const bf16x8*)(&sh_ab[lm][128] + kt * 32 + lq * 8);
      for (int nt = wv; nt < 22; nt += 8) {
        f32x4 acc = {0.f, 0.f, 0.f, 0.f};
        const bf16x8* bp = b6 + (size_t)(nt * 8) * 64 + lane;
        #pragma unroll
        for (int kt = 0; kt < 8; ++kt)
          acc = __builtin_amdgcn_mfma_f32_16x16x32_bf16(hfr[kt], bp[kt * 64], acc, 0, 0, 0);
        if (lq == 0) {
          int a = nt * 16 + lm;
          if (a < DAA) {
            float bias = Ws1_b[a];
            #pragma unroll
            for (int r = 0; r < 4; ++r) sh_s1[r][a] = tanhf(acc[r] + bias);
          }
        }
      }
    }
    __syncthreads();

    if (tid < 4 * DRR) {
      int rw = tid / DRR;
      int r = tid - rw * DRR;
      const float2* s2 = (const float2*)&sh_s1[rw][0];
      const float2* w2 = (const float2*)(Ws2_W + (size_t)r * DAA);
      float acc = 0.f;
      #pragma unroll 5
      for (int k = 0; k < 175; ++k) {
        float2 a = s2[k], b = w2[k];
        acc = fmaf(a.x, b.x, fmaf(a.y, b.y, acc));
      }
      float sc = acc + Ws2_b[r];
      float Mo = sh_M[rw][r];
      float Mn = fmaxf(Mo, sc);
      float scl = expf(Mo - Mn);
      float w = expf(sc - Mn);
      sh_M[rw][r] = Mn;
      sh_L[rw][r] = sh_L[rw][r] * scl + w;
      sh_scale[rw][r] = scl;
      sh_w[rw][r] = w;
    }
    __syncthreads();

    #pragma unroll
    for (int r = 0; r < DRR; ++r) {
      float scl = sh_scale[row][r];
      float w = sh_w[row][r];
      OA[r]  = OA[r]  * scl + w * hnA;
      OBv[r] = OBv[r] * scl + w * hnB;
    }
  }

  float pA = 0.f, pB = 0.f;
  #pragma unroll
  for (int r = 0; r < DRR; ++r) {
    float invL = 1.f / sh_L[row][r];
    pA += out_W[r * HD + jA] * (OA[r]  * invL);
    pB += out_W[r * HD + jB] * (OBv[r] * invL);
  }
  float* sred = &sh_s1[0][0];
  __syncthreads();
  sred[row * 256 + jA] = pA;
  sred[row * 256 + jB] = pB;
  __syncthreads();
  if (tid < 4) {
    float acc = 0.f;
    for (int k = 0; k < 256; ++k) acc += sred[tid * 256 + k];
    float yh = acc + out_b[0];
    int b = b0 + tid;
    float lab = labels[b], tr = is_train[b];
    float bce = fmaxf(yh, 0.f) - yh * lab + log1pf(expf(-fabsf(yh)));
    atomicAdd(&ws[1], bce * tr);
    out[1 + b] = 1.f / (1.f + expf(-yh));
  }
  __syncthreads();
  sred[tid] = (float)lossAcc;
  __syncthreads();
  for (int off = 256; off > 0; off >>= 1) {
    if (tid < off) sred[tid] += sred[tid + off];
    __syncthreads();
  }
  if (tid == 0) atomicAdd(&ws[0], sred[0]);
}

__global__ void final_kernel(const float* __restrict__ ws, float* __restrict__ out) {
  if (threadIdx.x == 0 && blockIdx.x == 0) {
    out[0] = ws[0] / (float)SS + 0.1f * (ws[1] / (ws[2] + 1e-5f));
  }
}

extern "C" void kernel_launch(void* const* d_in, const int* in_sizes, int n_in,
                              void* d_out, int out_size, void* d_ws, size_t ws_size,
                              hipStream_t stream) {
  const float* values   = (const float*)d_in[0];
  const float* masks    = (const float*)d_in[1];
  const float* deltas   = (const float*)d_in[2];
  const float* labels   = (const float*)d_in[3];
  const float* is_train = (const float*)d_in[4];
  const float* td_h_W   = (const float*)d_in[5];
  const float* td_h_b   = (const float*)d_in[6];
  const float* td_x_W   = (const float*)d_in[7];
  const float* td_x_b   = (const float*)d_in[8];
  const float* hist_W   = (const float*)d_in[9];
  const float* hist_b   = (const float*)d_in[10];
  const float* feat_W   = (const float*)d_in[11];
  const float* feat_b   = (const float*)d_in[12];
  const float* comb_W   = (const float*)d_in[13];
  const float* comb_b   = (const float*)d_in[14];
  const float* W_ih     = (const float*)d_in[15];
  const float* b_ih     = (const float*)d_in[16];
  const float* W_hh     = (const float*)d_in[17];
  const float* b_hh     = (const float*)d_in[18];
  const float* Ws1_W    = (const float*)d_in[19];
  const float* Ws1_b    = (const float*)d_in[20];
  const float* Ws2_W    = (const float*)d_in[21];
  const float* Ws2_b    = (const float*)d_in[22];
  const float* out_W    = (const float*)d_in[23];
  const float* out_b    = (const float*)d_in[24];
  float* out = (float*)d_out;
  float* ws  = (float*)d_ws;

  short* b5 = (short*)((char*)d_ws + WS_B5_OFS);
  short* b6 = (short*)((char*)d_ws + WS_B6_OFS);
  short* b3 = (short*)((char*)d_ws + WS_B3_OFS);
  short* b2 = (short*)((char*)d_ws + WS_B2_OFS);
  short* b7 = (short*)((char*)d_ws + WS_B7_OFS);

  convert_weights<<<(CW_TOTAL + 255) / 256, 256, 0, stream>>>(
      W_ih, W_hh, Ws1_W, hist_W, td_h_W, Ws2_W, b5, b6, b3, b2, b7);
  prep_kernel<<<SS, 256, 0, stream>>>(masks, is_train, ws);

  if (ws_size >= (size_t)WS_H_OFS + WS_H_BYTES) {
    rits_scan<<<BB / RPB, 512, 0, stream>>>(
        values, masks, deltas,
        td_h_b, td_x_W, td_x_b, hist_b, feat_W, feat_b, comb_W, comb_b,
        b_ih, b_hh, out, ws);
    rits_attn<<<BB, 256, 0, stream>>>(
        labels, is_train, Ws1_b, out_W, out_b, out, ws);
  } else {
    rits_fused<<<BB / 4, 512, 0, stream>>>(
        values, masks, deltas, labels, is_train,
        td_h_b, td_x_W, td_x_b, hist_b, feat_W, feat_b, comb_W, comb_b,
        b_ih, b_hh, Ws1_b, Ws2_W, Ws2_b, out_W, out_b, out, ws);
  }
  final_kernel<<<1, 64, 0, stream>>>(ws, out);
}